// Round 9
// baseline (532.846 us; speedup 1.0000x reference)
//
#include <hip/hip_runtime.h>
#include <math.h>

typedef __attribute__((ext_vector_type(8))) short short8;
typedef __attribute__((ext_vector_type(4))) float f32x4;
typedef unsigned int uint;
typedef unsigned short ushort;

#define HGRID(n, b) (((n) + (b) - 1) / (b))

__device__ __forceinline__ ushort f2bu(float f) {
    uint x = __builtin_bit_cast(uint, f);
    x = (x + 0x7fffu + ((x >> 16) & 1u)) >> 16;
    return (ushort)x;
}
__device__ __forceinline__ float blo(uint u) {   // low bf16 half -> float
    return __builtin_bit_cast(float, u << 16);
}
__device__ __forceinline__ float bhi(uint u) {   // high bf16 half -> float
    return __builtin_bit_cast(float, u & 0xffff0000u);
}
__device__ __forceinline__ uint packbf(float a, float b) {
    return (uint)f2bu(a) | ((uint)f2bu(b) << 16);
}

// async global->LDS, 16 B per lane; LDS dest = wave-uniform base + lane*16
__device__ __forceinline__ void gload16(const void* g, void* l) {
    __builtin_amdgcn_global_load_lds(
        (const __attribute__((address_space(1))) void*)g,
        (__attribute__((address_space(3))) void*)l, 16, 0, 0);
}

// ---------------- init ----------------

__global__ void init_kernel(int* __restrict__ cnt, int* __restrict__ cur,
                            float* __restrict__ gbuf, int N, int GH) {
    int i = blockIdx.x * 256 + threadIdx.x;
    if (i < N) { cnt[i] = 0; cur[i] = 0; }
    if (i < GH) gbuf[i] = 0.f;
}

// ---------------- CSR build ----------------

__global__ void count_kernel(const int* __restrict__ dst, int* __restrict__ cnt, int E) {
    int e = blockIdx.x * 256 + threadIdx.x;
    if (e < E) atomicAdd(&cnt[dst[e]], 1);
}

__global__ void scan_part(const int* __restrict__ cnt, int* __restrict__ bsum, int N) {
    __shared__ int sh[256];
    int b = blockIdx.x, t = threadIdx.x;
    int base = b * 1024 + t * 4;
    int tsum = 0;
    if (base + 3 < N) {
        int4 v = *(const int4*)(cnt + base);
        tsum = v.x + v.y + v.z + v.w;
    } else {
        #pragma unroll
        for (int k = 0; k < 4; ++k) if (base + k < N) tsum += cnt[base + k];
    }
    sh[t] = tsum;
    __syncthreads();
    for (int d = 128; d > 0; d >>= 1) {
        if (t < d) sh[t] += sh[t + d];
        __syncthreads();
    }
    if (t == 0) bsum[b] = sh[0];
}

__global__ void scan_fill(const int* __restrict__ cnt, const int* __restrict__ bsum,
                          int* __restrict__ offs, float* __restrict__ dinv,
                          int N, int E) {
    __shared__ int sh[256];
    __shared__ int sbase;
    int b = blockIdx.x, t = threadIdx.x;

    if (t < 64) {
        int s = 0;
        for (int i = t; i < b; i += 64) s += bsum[i];
        #pragma unroll
        for (int d = 32; d > 0; d >>= 1) s += __shfl_down(s, d, 64);
        if (t == 0) sbase = s;
    }

    int base = b * 1024 + t * 4;
    int c[4] = {0, 0, 0, 0};
    if (base + 3 < N) {
        int4 v = *(const int4*)(cnt + base);
        c[0] = v.x; c[1] = v.y; c[2] = v.z; c[3] = v.w;
    } else {
        #pragma unroll
        for (int k = 0; k < 4; ++k) if (base + k < N) c[k] = cnt[base + k];
    }
    int tsum = c[0] + c[1] + c[2] + c[3];
    sh[t] = tsum;
    __syncthreads();
    for (int d = 1; d < 256; d <<= 1) {
        int o = (t >= d) ? sh[t - d] : 0;
        __syncthreads();
        sh[t] += o;
        __syncthreads();
    }
    int run = sbase + sh[t] - tsum;
    #pragma unroll
    for (int k = 0; k < 4; ++k) {
        if (base + k < N) {
            offs[base + k] = run;
            dinv[base + k] = rsqrtf((float)c[k] + 1.0f);
            run += c[k];
        }
    }
    if (b == 0 && t == 0) offs[N] = E;
}

// fill edge records {src*64 (uint2 index), dinv[src]} grouped by dst
__global__ void fill_kernel(const int* __restrict__ src, const int* __restrict__ dst,
                            const int* __restrict__ offs, int* __restrict__ cur,
                            const float* __restrict__ dinv, int2* __restrict__ epack, int E) {
    int e = blockIdx.x * 256 + threadIdx.x;
    if (e < E) {
        int d = dst[e];
        int sv = src[e];
        int p = offs[d] + atomicAdd(&cur[d], 1);
        epack[p] = make_int2(sv * 64, __float_as_int(dinv[sv]));
    }
}

// ---------------- merged preprocessing ----------------

struct PrepArgs {
    const float *x, *s;
    const float *pre_w, *pre_b, *emb_w, *emb_b, *gin_w1, *gcn_w, *gin_w2, *whp_w;
    ushort *xs, *Wt_preemb, *Wt_dual, *Wt_gin2, *Wt_whp;
    float *bias_comb;
    int L, N;
};

__global__ void prep_kernel(PrepArgs a) {
    long idx = (long)blockIdx.x * 256 + threadIdx.x;
    long nconv = (long)a.N * 24;
    if (idx < nconv) {
        int n = (int)(idx / 24), ch = (int)(idx % 24);
        uint4 o = {0u, 0u, 0u, 0u};
        if (ch < 16) {
            const float4* px = (const float4*)(a.x + (long)n * 128 + ch * 8);
            float4 u = px[0], v = px[1];
            o.x = packbf(u.x, u.y); o.y = packbf(u.z, u.w);
            o.z = packbf(v.x, v.y); o.w = packbf(v.z, v.w);
        } else if (ch < 18) {
            const float4* ps = (const float4*)(a.s + (long)n * 16 + (ch - 16) * 8);
            float4 u = ps[0], v = ps[1];
            o.x = packbf(u.x, u.y); o.y = packbf(u.z, u.w);
            o.z = packbf(v.x, v.y); o.w = packbf(v.z, v.w);
        }
        *(uint4*)(a.xs + idx * 8) = o;
        return;
    }
    idx -= nconv;
    if (idx < 49152) {
        int c = (int)(idx / 192), k = (int)(idx % 192);
        float v = 0.f;
        if (c < 128) { if (k < 128) v = a.pre_w[(long)k * 128 + c]; }
        else if (k >= 128 && k < 144) v = a.emb_w[(long)(k - 128) * 128 + (c - 128)];
        a.Wt_preemb[idx] = f2bu(v);
        return;
    }
    idx -= 49152;
    if (idx < (long)a.L * 65536) {
        int i = (int)(idx / 65536);
        int r = (int)(idx % 65536);
        int c = r / 256, k = r % 256;
        float v = 0.f;
        if (c < 128) v = a.gin_w1[(long)i * 32768 + (long)k * 128 + c];
        else if (k >= 128) v = a.gcn_w[(long)i * 16384 + (long)(k - 128) * 128 + (c - 128)];
        a.Wt_dual[idx] = f2bu(v);
        return;
    }
    idx -= (long)a.L * 65536;
    if (idx < (long)a.L * 16384) {
        int i = (int)(idx / 16384);
        int r = (int)(idx % 16384);
        int c = r / 128, k = r % 128;
        a.Wt_gin2[idx] = f2bu(a.gin_w2[(long)i * 16384 + (long)k * 128 + c]);
        return;
    }
    idx -= (long)a.L * 16384;
    if (idx < 32768) {
        int c = (int)(idx / 256), k = (int)(idx % 256);
        a.Wt_whp[idx] = f2bu(a.whp_w[(long)k * 128 + c]);
        return;
    }
    idx -= 32768;
    if (idx < 256) a.bias_comb[idx] = (idx < 128) ? a.pre_b[idx] : a.emb_b[idx - 128];
}

// ---------------- unified MFMA linear: BM=128, 8 waves, global_load_lds staging ----------------

template<int KPAD, int BN>
__global__ __launch_bounds__(512) void lin_mfma(
    const ushort* __restrict__ A, int a_stride,
    const ushort* __restrict__ Wt, const float* __restrict__ bias,
    ushort* __restrict__ out, int o_stride, int N, int act, int interleaved)
{
    constexpr int BK = 64;
    constexpr int NF = BN / 64;
    __shared__ __align__(16) ushort LA[128][BK];
    __shared__ __align__(16) ushort LB[BN][BK];

    const int tid  = threadIdx.x;
    const int l    = tid & 63;
    const int w    = tid >> 6;
    const int wr   = w >> 2;
    const int wc   = w & 3;
    const int row0 = blockIdx.x * 128;
    const int l15  = l & 15;
    const int lhi  = l >> 4;
    const int lrow = l >> 3;
    const int lslot = l & 7;

    f32x4 acc[4][NF];
    #pragma unroll
    for (int m = 0; m < 4; ++m)
        #pragma unroll
        for (int n = 0; n < NF; ++n) acc[m][n] = (f32x4){0.f, 0.f, 0.f, 0.f};

    for (int k0 = 0; k0 < KPAD; k0 += BK) {
        __syncthreads();
        #pragma unroll
        for (int i = 0; i < 2; ++i) {
            int ci = w * 2 + i;
            int r  = ci * 8 + lrow;
            int gr = row0 + r; if (gr > N - 1) gr = N - 1;
            gload16(A + (long)gr * a_stride + k0 + ((lslot ^ (r & 7)) * 8), &LA[ci * 8][0]);
        }
        #pragma unroll
        for (int i = 0; i < NF; ++i) {
            int ci = w * NF + i;
            int c  = ci * 8 + lrow;
            gload16(Wt + (long)c * KPAD + k0 + ((lslot ^ (c & 7)) * 8), &LB[ci * 8][0]);
        }
        __syncthreads();
        #pragma unroll
        for (int kk = 0; kk < BK; kk += 32) {
            int chb = (kk >> 3) + lhi;
            short8 a[4];
            #pragma unroll
            for (int m = 0; m < 4; ++m) {
                int r = wr * 64 + m * 16 + l15;
                a[m] = *(const short8*)&LA[r][(chb ^ (r & 7)) * 8];
            }
            #pragma unroll
            for (int n = 0; n < NF; ++n) {
                int c = wc * (BN / 4) + n * 16 + l15;
                short8 b = *(const short8*)&LB[c][(chb ^ (c & 7)) * 8];
                #pragma unroll
                for (int m = 0; m < 4; ++m)
                    acc[m][n] = __builtin_amdgcn_mfma_f32_16x16x32_bf16(a[m], b, acc[m][n], 0, 0, 0);
            }
        }
    }

    #pragma unroll
    for (int n = 0; n < NF; ++n) {
        int col = wc * (BN / 4) + n * 16 + l15;
        float bv = bias ? bias[col] : 0.f;
        #pragma unroll
        for (int m = 0; m < 4; ++m) {
            #pragma unroll
            for (int j = 0; j < 4; ++j) {
                int gr = row0 + wr * 64 + m * 16 + (lhi << 2) + j;
                if (gr < N) {
                    float v = acc[m][n][j] + bv;
                    if (act) v = fmaxf(v, 0.f);
                    long off;
                    if (interleaved) {
                        int cc = col & 127;
                        off = (long)gr * 256 + 4 * (cc >> 1) + ((col >> 7) << 1) + (cc & 1);
                    } else {
                        off = (long)gr * o_stride + col;
                    }
                    out[off] = f2bu(v);
                }
            }
        }
    }
}

// ---------------- fused GIN+GCN gather, XCD channel-slice partitioned ----------------
// slice = blockIdx.x & 7 selects 64B of each 512B yh row; with round-robin block->XCD
// mapping each XCD's L2 working set is 25.6/8 = 3.2 MB (fits 4 MB L2).
// 8-lane group per node-slice, 32 nodes per 256-thread block, masked unroll-4 edge loop.
// Correctness is independent of the XCD mapping (slice only selects channels).

__global__ __launch_bounds__(256) void fused_gather(
    const uint2* __restrict__ yh, const int* __restrict__ offs,
    const int2* __restrict__ epack,
    const float* __restrict__ dinv,
    const float* __restrict__ b1, const float* __restrict__ gb,
    uint* __restrict__ h1p, uint* __restrict__ xcp, int N)
{
    int sb    = blockIdx.x;
    int slice = sb & 7;
    int node  = (sb >> 3) * 32 + (threadIdx.x >> 3);
    if (node >= N) return;
    int lg = threadIdx.x & 7;
    int w  = slice * 8 + lg;              // word index within the 64-uint2 row

    uint2 self = yh[(long)node * 64 + w];
    float di = dinv[node];
    float g0 = blo(self.x), g1 = bhi(self.x);
    float s0 = 0.f, s1 = 0.f;

    int j0 = offs[node], j1 = offs[node + 1];
    for (int j = j0; j < j1; j += 4) {
        int2 e[4]; uint2 v[4];
        #pragma unroll
        for (int k = 0; k < 4; ++k) {
            int jj = j + k;
            e[k] = epack[(jj < j1) ? jj : (j1 - 1)];
            if (jj >= j1) e[k].y = 0;
        }
        #pragma unroll
        for (int k = 0; k < 4; ++k) v[k] = yh[e[k].x + w];
        #pragma unroll
        for (int k = 0; k < 4; ++k) {
            float ds = __int_as_float(e[k].y);
            float m = (j + k < j1) ? 1.f : 0.f;
            g0 += blo(v[k].x) * m;
            g1 += bhi(v[k].x) * m;
            s0 += blo(v[k].y) * ds;
            s1 += bhi(v[k].y) * ds;
        }
    }

    float2 bb = ((const float2*)b1)[w];
    g0 = fmaxf(g0 + bb.x, 0.f);
    g1 = fmaxf(g1 + bb.y, 0.f);
    h1p[(long)node * 64 + w] = packbf(g0, g1);

    float dii = di * di;
    float2 gg = ((const float2*)gb)[w];
    float t0 = tanhf(s0 * di + blo(self.y) * dii + gg.x);
    float t1 = tanhf(s1 * di + bhi(self.y) * dii + gg.y);
    xcp[(long)node * 128 + 64 + w] = packbf(t0, t1);
}

// ---------------- pooling ----------------

__global__ void pool_kernel(const ushort* __restrict__ xh, const int* __restrict__ batch,
                            float* __restrict__ g, int N) {
    int c  = threadIdx.x;
    int n0 = blockIdx.x * 128;
    if (n0 >= N) return;
    int n1 = min(n0 + 128, N);
    int curg = batch[n0];
    float acc = 0.f;
    for (int n = n0; n < n1; ++n) {
        int b = batch[n];
        if (b != curg) {
            atomicAdd(&g[(long)curg * 128 + c], acc);
            acc = 0.f;
            curg = b;
        }
        acc += blo((uint)xh[(long)n * 128 + c]);
    }
    atomicAdd(&g[(long)curg * 128 + c], acc);
}

// ---------------- head ----------------

__global__ void head_kernel(const float* __restrict__ g, const float* __restrict__ post_w,
                            const float* __restrict__ post_b, const float* __restrict__ ro_w,
                            const float* __restrict__ ro_b, float* __restrict__ out, int C) {
    __shared__ float row[128];
    __shared__ float g2[128];
    __shared__ float lg[16];
    __shared__ float s_lse;
    int gi = blockIdx.x;
    int c  = threadIdx.x;
    row[c] = g[(long)gi * 128 + c];
    __syncthreads();
    float acc = post_b[c];
    for (int k = 0; k < 128; ++k) acc += row[k] * post_w[k * 128 + c];
    g2[c] = fmaxf(acc, 0.f);
    __syncthreads();
    if (c < C) {
        float a = ro_b[c];
        for (int k = 0; k < 128; ++k) a += g2[k] * ro_w[k * C + c];
        lg[c] = a;
    }
    __syncthreads();
    if (c == 0) {
        float m = lg[0];
        for (int i = 1; i < C; ++i) m = fmaxf(m, lg[i]);
        float sum = 0.f;
        for (int i = 0; i < C; ++i) sum += expf(lg[i] - m);
        s_lse = m + logf(sum);
    }
    __syncthreads();
    if (c < C) out[(long)gi * C + c] = lg[c] - s_lse;
}

// ---------------- launch ----------------

extern "C" void kernel_launch(void* const* d_in, const int* in_sizes, int n_in,
                              void* d_out, int out_size, void* d_ws, size_t ws_size,
                              hipStream_t stream) {
    const float* x      = (const float*)d_in[0];
    const float* s_in   = (const float*)d_in[1];
    const int*   ei     = (const int*)d_in[2];
    const int*   batch  = (const int*)d_in[3];
    const float* pre_w  = (const float*)d_in[4];
    const float* pre_b  = (const float*)d_in[5];
    const float* emb_w  = (const float*)d_in[6];
    const float* emb_b  = (const float*)d_in[7];
    const float* gin_w1 = (const float*)d_in[8];
    const float* gin_b1 = (const float*)d_in[9];
    const float* gin_w2 = (const float*)d_in[10];
    const float* gin_b2 = (const float*)d_in[11];
    const float* gcn_w  = (const float*)d_in[12];
    const float* gcn_b  = (const float*)d_in[13];
    const float* whp_w  = (const float*)d_in[14];
    const float* whp_b  = (const float*)d_in[15];
    const float* post_w = (const float*)d_in[16];
    const float* post_b = (const float*)d_in[17];
    const float* ro_w   = (const float*)d_in[18];
    const float* ro_b   = (const float*)d_in[19];

    const int H = 128;
    const int N = in_sizes[0] / 128;
    const int E = in_sizes[2] / 2;
    const int C = in_sizes[19];
    const int G = out_size / C;
    const int L = in_sizes[9] / H;

    const int* srcv = ei;
    const int* dstv = ei + E;

    char* p = (char*)d_ws;
    auto alloc = [&](size_t bytes) -> void* {
        void* r = (void*)p;
        p += (bytes + 255) & ~(size_t)255;
        return r;
    };
    ushort* xc   = (ushort*)alloc((size_t)N * 256 * 2);
    ushort* yh   = (ushort*)alloc((size_t)N * 256 * 2);
    ushort* h1   = (ushort*)alloc((size_t)N * 128 * 2);
    ushort* xs   = (ushort*)alloc((size_t)N * 192 * 2);
    ushort* ybuf = (ushort*)alloc((size_t)N * 128 * 2);
    ushort* Wt_preemb = (ushort*)alloc(256 * 192 * 2);
    ushort* Wt_dual   = (ushort*)alloc((size_t)L * 256 * 256 * 2);
    ushort* Wt_gin2   = (ushort*)alloc((size_t)L * 128 * 128 * 2);
    ushort* Wt_whp    = (ushort*)alloc(128 * 256 * 2);
    float*  bias_comb = (float*)alloc(256 * 4);
    float*  dinv = (float*)alloc((size_t)N * 4);
    float*  gbuf = (float*)alloc((size_t)G * 128 * 4);
    int* cnt   = (int*)alloc((size_t)N * 4);
    int* offs  = (int*)alloc((size_t)(N + 1) * 4);
    int* cur   = (int*)alloc((size_t)N * 4);
    int* bsum  = (int*)alloc((size_t)HGRID(N, 1024) * 4);
    int2* epack = (int2*)alloc((size_t)E * 8);

    const int nb = HGRID(N, 1024);

    init_kernel<<<HGRID(N, 256), 256, 0, stream>>>(cnt, cur, gbuf, N, G * 128);
    count_kernel<<<HGRID(E, 256), 256, 0, stream>>>(dstv, cnt, E);
    scan_part<<<nb, 256, 0, stream>>>(cnt, bsum, N);
    scan_fill<<<nb, 256, 0, stream>>>(cnt, bsum, offs, dinv, N, E);
    fill_kernel<<<HGRID(E, 256), 256, 0, stream>>>(srcv, dstv, offs, cur, dinv, epack, E);

    PrepArgs pa;
    pa.x = x; pa.s = s_in;
    pa.pre_w = pre_w; pa.pre_b = pre_b; pa.emb_w = emb_w; pa.emb_b = emb_b;
    pa.gin_w1 = gin_w1; pa.gcn_w = gcn_w; pa.gin_w2 = gin_w2; pa.whp_w = whp_w;
    pa.xs = xs; pa.Wt_preemb = Wt_preemb; pa.Wt_dual = Wt_dual; pa.Wt_gin2 = Wt_gin2;
    pa.Wt_whp = Wt_whp; pa.bias_comb = bias_comb; pa.L = L; pa.N = N;
    long prep_tot = (long)N * 24 + 49152 + (long)L * 65536 + (long)L * 16384 + 32768 + 256;
    prep_kernel<<<HGRID(prep_tot, 256), 256, 0, stream>>>(pa);

    const int lb = HGRID(N, 128);
    lin_mfma<192, 256><<<lb, 512, 0, stream>>>(xs, 192, Wt_preemb, bias_comb,
                                               xc, 256, N, 0, 0);

    const int gb_blocks = HGRID(N, 32) * 8;
    for (int i = 0; i < L; ++i) {
        lin_mfma<256, 256><<<lb, 512, 0, stream>>>(xc, 256, Wt_dual + (size_t)i * 65536,
                                                   nullptr, yh, 256, N, 0, 1);
        fused_gather<<<gb_blocks, 256, 0, stream>>>(
            (const uint2*)yh, offs, epack, dinv,
            gin_b1 + (size_t)i * H, gcn_b + (size_t)i * H,
            (uint*)h1, (uint*)xc, N);
        lin_mfma<128, 128><<<lb, 512, 0, stream>>>(h1, 128, Wt_gin2 + (size_t)i * 16384,
                                                   gin_b2 + (size_t)i * H, xc, 256, N, 1, 0);
    }

    lin_mfma<256, 128><<<lb, 512, 0, stream>>>(xc, 256, Wt_whp, whp_b, ybuf, 128, N, 0, 0);

    pool_kernel<<<HGRID(N, 128), 128, 0, stream>>>(ybuf, batch, gbuf, N);
    head_kernel<<<G, 128, 0, stream>>>(gbuf, post_w, post_b, ro_w, ro_b, (float*)d_out, C);
}

// Round 10
// 431.146 us; speedup vs baseline: 1.2359x; 1.2359x over previous
//
#include <hip/hip_runtime.h>
#include <math.h>

typedef __attribute__((ext_vector_type(8))) short short8;
typedef __attribute__((ext_vector_type(4))) float f32x4;
typedef unsigned int uint;
typedef unsigned short ushort;

#define HGRID(n, b) (((n) + (b) - 1) / (b))

__device__ __forceinline__ ushort f2bu(float f) {
    uint x = __builtin_bit_cast(uint, f);
    x = (x + 0x7fffu + ((x >> 16) & 1u)) >> 16;
    return (ushort)x;
}
__device__ __forceinline__ float blo(uint u) {   // low bf16 half -> float
    return __builtin_bit_cast(float, u << 16);
}
__device__ __forceinline__ float bhi(uint u) {   // high bf16 half -> float
    return __builtin_bit_cast(float, u & 0xffff0000u);
}
__device__ __forceinline__ uint packbf(float a, float b) {
    return (uint)f2bu(a) | ((uint)f2bu(b) << 16);
}

// async global->LDS, 16 B per lane; LDS dest = wave-uniform base + lane*16
__device__ __forceinline__ void gload16(const void* g, void* l) {
    __builtin_amdgcn_global_load_lds(
        (const __attribute__((address_space(1))) void*)g,
        (__attribute__((address_space(3))) void*)l, 16, 0, 0);
}

// ---------------- init ----------------

__global__ void init_kernel(int* __restrict__ cnt, int* __restrict__ cur,
                            float* __restrict__ gbuf, int N, int GH) {
    int i = blockIdx.x * 256 + threadIdx.x;
    if (i < N) { cnt[i] = 0; cur[i] = 0; }
    if (i < GH) gbuf[i] = 0.f;
}

// ---------------- CSR build ----------------

__global__ void count_kernel(const int* __restrict__ dst, int* __restrict__ cnt, int E) {
    int e = blockIdx.x * 256 + threadIdx.x;
    if (e < E) atomicAdd(&cnt[dst[e]], 1);
}

__global__ void scan_part(const int* __restrict__ cnt, int* __restrict__ bsum, int N) {
    __shared__ int sh[256];
    int b = blockIdx.x, t = threadIdx.x;
    int base = b * 1024 + t * 4;
    int tsum = 0;
    if (base + 3 < N) {
        int4 v = *(const int4*)(cnt + base);
        tsum = v.x + v.y + v.z + v.w;
    } else {
        #pragma unroll
        for (int k = 0; k < 4; ++k) if (base + k < N) tsum += cnt[base + k];
    }
    sh[t] = tsum;
    __syncthreads();
    for (int d = 128; d > 0; d >>= 1) {
        if (t < d) sh[t] += sh[t + d];
        __syncthreads();
    }
    if (t == 0) bsum[b] = sh[0];
}

__global__ void scan_fill(const int* __restrict__ cnt, const int* __restrict__ bsum,
                          int* __restrict__ offs, float* __restrict__ dinv,
                          int N, int E) {
    __shared__ int sh[256];
    __shared__ int sbase;
    int b = blockIdx.x, t = threadIdx.x;

    if (t < 64) {
        int s = 0;
        for (int i = t; i < b; i += 64) s += bsum[i];
        #pragma unroll
        for (int d = 32; d > 0; d >>= 1) s += __shfl_down(s, d, 64);
        if (t == 0) sbase = s;
    }

    int base = b * 1024 + t * 4;
    int c[4] = {0, 0, 0, 0};
    if (base + 3 < N) {
        int4 v = *(const int4*)(cnt + base);
        c[0] = v.x; c[1] = v.y; c[2] = v.z; c[3] = v.w;
    } else {
        #pragma unroll
        for (int k = 0; k < 4; ++k) if (base + k < N) c[k] = cnt[base + k];
    }
    int tsum = c[0] + c[1] + c[2] + c[3];
    sh[t] = tsum;
    __syncthreads();
    for (int d = 1; d < 256; d <<= 1) {
        int o = (t >= d) ? sh[t - d] : 0;
        __syncthreads();
        sh[t] += o;
        __syncthreads();
    }
    int run = sbase + sh[t] - tsum;
    #pragma unroll
    for (int k = 0; k < 4; ++k) {
        if (base + k < N) {
            offs[base + k] = run;
            dinv[base + k] = rsqrtf((float)c[k] + 1.0f);
            run += c[k];
        }
    }
    if (b == 0 && t == 0) offs[N] = E;
}

// fill edge records {src*64 (uint2 index), dinv[src]} grouped by dst
__global__ void fill_kernel(const int* __restrict__ src, const int* __restrict__ dst,
                            const int* __restrict__ offs, int* __restrict__ cur,
                            const float* __restrict__ dinv, int2* __restrict__ epack, int E) {
    int e = blockIdx.x * 256 + threadIdx.x;
    if (e < E) {
        int d = dst[e];
        int sv = src[e];
        int p = offs[d] + atomicAdd(&cur[d], 1);
        epack[p] = make_int2(sv * 64, __float_as_int(dinv[sv]));
    }
}

// ---------------- merged preprocessing ----------------

struct PrepArgs {
    const float *x, *s;
    const float *pre_w, *pre_b, *emb_w, *emb_b, *gin_w1, *gcn_w, *gin_w2, *whp_w;
    ushort *xs, *Wt_preemb, *Wt_dual, *Wt_gin2, *Wt_whp;
    float *bias_comb;
    int L, N;
};

__global__ void prep_kernel(PrepArgs a) {
    long idx = (long)blockIdx.x * 256 + threadIdx.x;
    long nconv = (long)a.N * 24;
    if (idx < nconv) {
        int n = (int)(idx / 24), ch = (int)(idx % 24);
        uint4 o = {0u, 0u, 0u, 0u};
        if (ch < 16) {
            const float4* px = (const float4*)(a.x + (long)n * 128 + ch * 8);
            float4 u = px[0], v = px[1];
            o.x = packbf(u.x, u.y); o.y = packbf(u.z, u.w);
            o.z = packbf(v.x, v.y); o.w = packbf(v.z, v.w);
        } else if (ch < 18) {
            const float4* ps = (const float4*)(a.s + (long)n * 16 + (ch - 16) * 8);
            float4 u = ps[0], v = ps[1];
            o.x = packbf(u.x, u.y); o.y = packbf(u.z, u.w);
            o.z = packbf(v.x, v.y); o.w = packbf(v.z, v.w);
        }
        *(uint4*)(a.xs + idx * 8) = o;
        return;
    }
    idx -= nconv;
    if (idx < 49152) {
        int c = (int)(idx / 192), k = (int)(idx % 192);
        float v = 0.f;
        if (c < 128) { if (k < 128) v = a.pre_w[(long)k * 128 + c]; }
        else if (k >= 128 && k < 144) v = a.emb_w[(long)(k - 128) * 128 + (c - 128)];
        a.Wt_preemb[idx] = f2bu(v);
        return;
    }
    idx -= 49152;
    if (idx < (long)a.L * 65536) {
        int i = (int)(idx / 65536);
        int r = (int)(idx % 65536);
        int c = r / 256, k = r % 256;
        float v = 0.f;
        if (c < 128) v = a.gin_w1[(long)i * 32768 + (long)k * 128 + c];
        else if (k >= 128) v = a.gcn_w[(long)i * 16384 + (long)(k - 128) * 128 + (c - 128)];
        a.Wt_dual[idx] = f2bu(v);
        return;
    }
    idx -= (long)a.L * 65536;
    if (idx < (long)a.L * 16384) {
        int i = (int)(idx / 16384);
        int r = (int)(idx % 16384);
        int c = r / 128, k = r % 128;
        a.Wt_gin2[idx] = f2bu(a.gin_w2[(long)i * 16384 + (long)k * 128 + c]);
        return;
    }
    idx -= (long)a.L * 16384;
    if (idx < 32768) {
        int c = (int)(idx / 256), k = (int)(idx % 256);
        a.Wt_whp[idx] = f2bu(a.whp_w[(long)k * 128 + c]);
        return;
    }
    idx -= 32768;
    if (idx < 256) a.bias_comb[idx] = (idx < 128) ? a.pre_b[idx] : a.emb_b[idx - 128];
}

// ---------------- unified MFMA linear: BM=128, 8 waves, global_load_lds staging ----------------

template<int KPAD, int BN>
__global__ __launch_bounds__(512) void lin_mfma(
    const ushort* __restrict__ A, int a_stride,
    const ushort* __restrict__ Wt, const float* __restrict__ bias,
    ushort* __restrict__ out, int o_stride, int N, int act, int interleaved)
{
    constexpr int BK = 64;
    constexpr int NF = BN / 64;
    __shared__ __align__(16) ushort LA[128][BK];
    __shared__ __align__(16) ushort LB[BN][BK];

    const int tid  = threadIdx.x;
    const int l    = tid & 63;
    const int w    = tid >> 6;
    const int wr   = w >> 2;
    const int wc   = w & 3;
    const int row0 = blockIdx.x * 128;
    const int l15  = l & 15;
    const int lhi  = l >> 4;
    const int lrow = l >> 3;
    const int lslot = l & 7;

    f32x4 acc[4][NF];
    #pragma unroll
    for (int m = 0; m < 4; ++m)
        #pragma unroll
        for (int n = 0; n < NF; ++n) acc[m][n] = (f32x4){0.f, 0.f, 0.f, 0.f};

    for (int k0 = 0; k0 < KPAD; k0 += BK) {
        __syncthreads();
        #pragma unroll
        for (int i = 0; i < 2; ++i) {
            int ci = w * 2 + i;
            int r  = ci * 8 + lrow;
            int gr = row0 + r; if (gr > N - 1) gr = N - 1;
            gload16(A + (long)gr * a_stride + k0 + ((lslot ^ (r & 7)) * 8), &LA[ci * 8][0]);
        }
        #pragma unroll
        for (int i = 0; i < NF; ++i) {
            int ci = w * NF + i;
            int c  = ci * 8 + lrow;
            gload16(Wt + (long)c * KPAD + k0 + ((lslot ^ (c & 7)) * 8), &LB[ci * 8][0]);
        }
        __syncthreads();
        #pragma unroll
        for (int kk = 0; kk < BK; kk += 32) {
            int chb = (kk >> 3) + lhi;
            short8 a[4];
            #pragma unroll
            for (int m = 0; m < 4; ++m) {
                int r = wr * 64 + m * 16 + l15;
                a[m] = *(const short8*)&LA[r][(chb ^ (r & 7)) * 8];
            }
            #pragma unroll
            for (int n = 0; n < NF; ++n) {
                int c = wc * (BN / 4) + n * 16 + l15;
                short8 b = *(const short8*)&LB[c][(chb ^ (c & 7)) * 8];
                #pragma unroll
                for (int m = 0; m < 4; ++m)
                    acc[m][n] = __builtin_amdgcn_mfma_f32_16x16x32_bf16(a[m], b, acc[m][n], 0, 0, 0);
            }
        }
    }

    #pragma unroll
    for (int n = 0; n < NF; ++n) {
        int col = wc * (BN / 4) + n * 16 + l15;
        float bv = bias ? bias[col] : 0.f;
        #pragma unroll
        for (int m = 0; m < 4; ++m) {
            #pragma unroll
            for (int j = 0; j < 4; ++j) {
                int gr = row0 + wr * 64 + m * 16 + (lhi << 2) + j;
                if (gr < N) {
                    float v = acc[m][n][j] + bv;
                    if (act) v = fmaxf(v, 0.f);
                    long off;
                    if (interleaved) {
                        int cc = col & 127;
                        off = (long)gr * 256 + 4 * (cc >> 1) + ((col >> 7) << 1) + (cc & 1);
                    } else {
                        off = (long)gr * o_stride + col;
                    }
                    out[off] = f2bu(v);
                }
            }
        }
    }
}

// ---------------- fused GIN+GCN gather (round-8 structure + scalar edge loads) ----------------
// 4 nodes/block, 256 thr, unroll-8 + masked tail.
// epack.x = src*64 (uint2 index base), epack.y = dinv[src] bits.
// j0/j1 are wave-uniform (node = tid>>6); readfirstlane makes them SGPR so the
// epack records compile to s_load, freeing VMEM slots for the random yh gathers.

__global__ __launch_bounds__(256) void fused_gather(
    const uint2* __restrict__ yh, const int* __restrict__ offs,
    const int2* __restrict__ epack,
    const float* __restrict__ dinv,
    const float* __restrict__ b1, const float* __restrict__ gb,
    uint* __restrict__ h1p, uint* __restrict__ xcp, int N)
{
    int node = blockIdx.x * 4 + (threadIdx.x >> 6);
    if (node >= N) return;
    node = __builtin_amdgcn_readfirstlane(node);
    int l = threadIdx.x & 63;

    uint2 self = yh[(long)node * 64 + l];
    float di = dinv[node];
    float g0 = blo(self.x), g1 = bhi(self.x);
    float s0 = 0.f, s1 = 0.f;

    int j0 = __builtin_amdgcn_readfirstlane(offs[node]);
    int j1 = __builtin_amdgcn_readfirstlane(offs[node + 1]);
    int jmid = j0 + ((j1 - j0) & ~7);

    for (int j = j0; j < jmid; j += 8) {
        int2 e[8]; uint2 v[8];
        #pragma unroll
        for (int k = 0; k < 8; ++k) e[k] = epack[j + k];
        #pragma unroll
        for (int k = 0; k < 8; ++k) v[k] = yh[e[k].x + l];
        #pragma unroll
        for (int k = 0; k < 8; ++k) {
            float ds = __int_as_float(e[k].y);
            g0 += blo(v[k].x);
            g1 += bhi(v[k].x);
            s0 += blo(v[k].y) * ds;
            s1 += bhi(v[k].y) * ds;
        }
    }
    if (jmid < j1) {                       // masked batch of 8
        int2 e[8]; uint2 v[8];
        #pragma unroll
        for (int k = 0; k < 8; ++k) {
            int jj = jmid + k;
            e[k] = epack[(jj < j1) ? jj : (j1 - 1)];
            if (jj >= j1) e[k].y = 0;
        }
        #pragma unroll
        for (int k = 0; k < 8; ++k) v[k] = yh[e[k].x + l];
        #pragma unroll
        for (int k = 0; k < 8; ++k) {
            float ds = __int_as_float(e[k].y);
            float m = (jmid + k < j1) ? 1.f : 0.f;
            g0 += blo(v[k].x) * m;
            g1 += bhi(v[k].x) * m;
            s0 += blo(v[k].y) * ds;
            s1 += bhi(v[k].y) * ds;
        }
    }

    float2 bb = ((const float2*)b1)[l];
    g0 = fmaxf(g0 + bb.x, 0.f);
    g1 = fmaxf(g1 + bb.y, 0.f);
    h1p[(long)node * 64 + l] = packbf(g0, g1);

    float dii = di * di;
    float2 gg = ((const float2*)gb)[l];
    float t0 = tanhf(s0 * di + blo(self.y) * dii + gg.x);
    float t1 = tanhf(s1 * di + bhi(self.y) * dii + gg.y);
    xcp[(long)node * 128 + 64 + l] = packbf(t0, t1);
}

// ---------------- pooling ----------------

__global__ void pool_kernel(const ushort* __restrict__ xh, const int* __restrict__ batch,
                            float* __restrict__ g, int N) {
    int c  = threadIdx.x;
    int n0 = blockIdx.x * 128;
    if (n0 >= N) return;
    int n1 = min(n0 + 128, N);
    int curg = batch[n0];
    float acc = 0.f;
    for (int n = n0; n < n1; ++n) {
        int b = batch[n];
        if (b != curg) {
            atomicAdd(&g[(long)curg * 128 + c], acc);
            acc = 0.f;
            curg = b;
        }
        acc += blo((uint)xh[(long)n * 128 + c]);
    }
    atomicAdd(&g[(long)curg * 128 + c], acc);
}

// ---------------- head ----------------

__global__ void head_kernel(const float* __restrict__ g, const float* __restrict__ post_w,
                            const float* __restrict__ post_b, const float* __restrict__ ro_w,
                            const float* __restrict__ ro_b, float* __restrict__ out, int C) {
    __shared__ float row[128];
    __shared__ float g2[128];
    __shared__ float lg[16];
    __shared__ float s_lse;
    int gi = blockIdx.x;
    int c  = threadIdx.x;
    row[c] = g[(long)gi * 128 + c];
    __syncthreads();
    float acc = post_b[c];
    for (int k = 0; k < 128; ++k) acc += row[k] * post_w[k * 128 + c];
    g2[c] = fmaxf(acc, 0.f);
    __syncthreads();
    if (c < C) {
        float a = ro_b[c];
        for (int k = 0; k < 128; ++k) a += g2[k] * ro_w[k * C + c];
        lg[c] = a;
    }
    __syncthreads();
    if (c == 0) {
        float m = lg[0];
        for (int i = 1; i < C; ++i) m = fmaxf(m, lg[i]);
        float sum = 0.f;
        for (int i = 0; i < C; ++i) sum += expf(lg[i] - m);
        s_lse = m + logf(sum);
    }
    __syncthreads();
    if (c < C) out[(long)gi * C + c] = lg[c] - s_lse;
}

// ---------------- launch ----------------

extern "C" void kernel_launch(void* const* d_in, const int* in_sizes, int n_in,
                              void* d_out, int out_size, void* d_ws, size_t ws_size,
                              hipStream_t stream) {
    const float* x      = (const float*)d_in[0];
    const float* s_in   = (const float*)d_in[1];
    const int*   ei     = (const int*)d_in[2];
    const int*   batch  = (const int*)d_in[3];
    const float* pre_w  = (const float*)d_in[4];
    const float* pre_b  = (const float*)d_in[5];
    const float* emb_w  = (const float*)d_in[6];
    const float* emb_b  = (const float*)d_in[7];
    const float* gin_w1 = (const float*)d_in[8];
    const float* gin_b1 = (const float*)d_in[9];
    const float* gin_w2 = (const float*)d_in[10];
    const float* gin_b2 = (const float*)d_in[11];
    const float* gcn_w  = (const float*)d_in[12];
    const float* gcn_b  = (const float*)d_in[13];
    const float* whp_w  = (const float*)d_in[14];
    const float* whp_b  = (const float*)d_in[15];
    const float* post_w = (const float*)d_in[16];
    const float* post_b = (const float*)d_in[17];
    const float* ro_w   = (const float*)d_in[18];
    const float* ro_b   = (const float*)d_in[19];

    const int H = 128;
    const int N = in_sizes[0] / 128;
    const int E = in_sizes[2] / 2;
    const int C = in_sizes[19];
    const int G = out_size / C;
    const int L = in_sizes[9] / H;

    const int* srcv = ei;
    const int* dstv = ei + E;

    char* p = (char*)d_ws;
    auto alloc = [&](size_t bytes) -> void* {
        void* r = (void*)p;
        p += (bytes + 255) & ~(size_t)255;
        return r;
    };
    ushort* xc   = (ushort*)alloc((size_t)N * 256 * 2);
    ushort* yh   = (ushort*)alloc((size_t)N * 256 * 2);
    ushort* h1   = (ushort*)alloc((size_t)N * 128 * 2);
    ushort* xs   = (ushort*)alloc((size_t)N * 192 * 2);
    ushort* ybuf = (ushort*)alloc((size_t)N * 128 * 2);
    ushort* Wt_preemb = (ushort*)alloc(256 * 192 * 2);
    ushort* Wt_dual   = (ushort*)alloc((size_t)L * 256 * 256 * 2);
    ushort* Wt_gin2   = (ushort*)alloc((size_t)L * 128 * 128 * 2);
    ushort* Wt_whp    = (ushort*)alloc(128 * 256 * 2);
    float*  bias_comb = (float*)alloc(256 * 4);
    float*  dinv = (float*)alloc((size_t)N * 4);
    float*  gbuf = (float*)alloc((size_t)G * 128 * 4);
    int* cnt   = (int*)alloc((size_t)N * 4);
    int* offs  = (int*)alloc((size_t)(N + 1) * 4);
    int* cur   = (int*)alloc((size_t)N * 4);
    int* bsum  = (int*)alloc((size_t)HGRID(N, 1024) * 4);
    int2* epack = (int2*)alloc((size_t)E * 8);

    const int nb = HGRID(N, 1024);

    init_kernel<<<HGRID(N, 256), 256, 0, stream>>>(cnt, cur, gbuf, N, G * 128);
    count_kernel<<<HGRID(E, 256), 256, 0, stream>>>(dstv, cnt, E);
    scan_part<<<nb, 256, 0, stream>>>(cnt, bsum, N);
    scan_fill<<<nb, 256, 0, stream>>>(cnt, bsum, offs, dinv, N, E);
    fill_kernel<<<HGRID(E, 256), 256, 0, stream>>>(srcv, dstv, offs, cur, dinv, epack, E);

    PrepArgs pa;
    pa.x = x; pa.s = s_in;
    pa.pre_w = pre_w; pa.pre_b = pre_b; pa.emb_w = emb_w; pa.emb_b = emb_b;
    pa.gin_w1 = gin_w1; pa.gcn_w = gcn_w; pa.gin_w2 = gin_w2; pa.whp_w = whp_w;
    pa.xs = xs; pa.Wt_preemb = Wt_preemb; pa.Wt_dual = Wt_dual; pa.Wt_gin2 = Wt_gin2;
    pa.Wt_whp = Wt_whp; pa.bias_comb = bias_comb; pa.L = L; pa.N = N;
    long prep_tot = (long)N * 24 + 49152 + (long)L * 65536 + (long)L * 16384 + 32768 + 256;
    prep_kernel<<<HGRID(prep_tot, 256), 256, 0, stream>>>(pa);

    const int lb = HGRID(N, 128);
    lin_mfma<192, 256><<<lb, 512, 0, stream>>>(xs, 192, Wt_preemb, bias_comb,
                                               xc, 256, N, 0, 0);

    for (int i = 0; i < L; ++i) {
        lin_mfma<256, 256><<<lb, 512, 0, stream>>>(xc, 256, Wt_dual + (size_t)i * 65536,
                                                   nullptr, yh, 256, N, 0, 1);
        fused_gather<<<HGRID(N, 4), 256, 0, stream>>>(
            (const uint2*)yh, offs, epack, dinv,
            gin_b1 + (size_t)i * H, gcn_b + (size_t)i * H,
            (uint*)h1, (uint*)xc, N);
        lin_mfma<128, 128><<<lb, 512, 0, stream>>>(h1, 128, Wt_gin2 + (size_t)i * 16384,
                                                   gin_b2 + (size_t)i * H, xc, 256, N, 1, 0);
    }

    lin_mfma<256, 128><<<lb, 512, 0, stream>>>(xc, 256, Wt_whp, whp_b, ybuf, 128, N, 0, 0);

    pool_kernel<<<HGRID(N, 128), 128, 0, stream>>>(ybuf, batch, gbuf, N);
    head_kernel<<<G, 128, 0, stream>>>(gbuf, post_w, post_b, ro_w, ro_b, (float*)d_out, C);
}

// Round 11
// 423.623 us; speedup vs baseline: 1.2578x; 1.0178x over previous
//
#include <hip/hip_runtime.h>
#include <math.h>

typedef __attribute__((ext_vector_type(8))) short short8;
typedef __attribute__((ext_vector_type(4))) float f32x4;
typedef unsigned int uint;
typedef unsigned short ushort;

#define HGRID(n, b) (((n) + (b) - 1) / (b))

__device__ __forceinline__ ushort f2bu(float f) {
    uint x = __builtin_bit_cast(uint, f);
    x = (x + 0x7fffu + ((x >> 16) & 1u)) >> 16;
    return (ushort)x;
}
__device__ __forceinline__ float blo(uint u) {   // low bf16 half -> float
    return __builtin_bit_cast(float, u << 16);
}
__device__ __forceinline__ float bhi(uint u) {   // high bf16 half -> float
    return __builtin_bit_cast(float, u & 0xffff0000u);
}
__device__ __forceinline__ uint packbf(float a, float b) {
    return (uint)f2bu(a) | ((uint)f2bu(b) << 16);
}

// async global->LDS, 16 B per lane; LDS dest = wave-uniform base + lane*16
__device__ __forceinline__ void gload16(const void* g, void* l) {
    __builtin_amdgcn_global_load_lds(
        (const __attribute__((address_space(1))) void*)g,
        (__attribute__((address_space(3))) void*)l, 16, 0, 0);
}

// ---------------- init ----------------

__global__ void init_kernel(int* __restrict__ cnt, int* __restrict__ cur,
                            float* __restrict__ gsum, int* __restrict__ cntg,
                            int N, int GH, int G) {
    int i = blockIdx.x * 256 + threadIdx.x;
    if (i < N) { cnt[i] = 0; cur[i] = 0; }
    if (i < GH) gsum[i] = 0.f;
    if (i < G) cntg[i] = 0;
}

// ---------------- CSR build ----------------

__global__ void count_kernel(const int* __restrict__ dst, int* __restrict__ cnt, int E) {
    int e = blockIdx.x * 256 + threadIdx.x;
    if (e < E) atomicAdd(&cnt[dst[e]], 1);
}

__global__ void scan_part(const int* __restrict__ cnt, int* __restrict__ bsum, int N) {
    __shared__ int sh[256];
    int b = blockIdx.x, t = threadIdx.x;
    int base = b * 1024 + t * 4;
    int tsum = 0;
    if (base + 3 < N) {
        int4 v = *(const int4*)(cnt + base);
        tsum = v.x + v.y + v.z + v.w;
    } else {
        #pragma unroll
        for (int k = 0; k < 4; ++k) if (base + k < N) tsum += cnt[base + k];
    }
    sh[t] = tsum;
    __syncthreads();
    for (int d = 128; d > 0; d >>= 1) {
        if (t < d) sh[t] += sh[t + d];
        __syncthreads();
    }
    if (t == 0) bsum[b] = sh[0];
}

__global__ void scan_fill(const int* __restrict__ cnt, const int* __restrict__ bsum,
                          int* __restrict__ offs, float* __restrict__ dinv,
                          int N, int E) {
    __shared__ int sh[256];
    __shared__ int sbase;
    int b = blockIdx.x, t = threadIdx.x;

    if (t < 64) {
        int s = 0;
        for (int i = t; i < b; i += 64) s += bsum[i];
        #pragma unroll
        for (int d = 32; d > 0; d >>= 1) s += __shfl_down(s, d, 64);
        if (t == 0) sbase = s;
    }

    int base = b * 1024 + t * 4;
    int c[4] = {0, 0, 0, 0};
    if (base + 3 < N) {
        int4 v = *(const int4*)(cnt + base);
        c[0] = v.x; c[1] = v.y; c[2] = v.z; c[3] = v.w;
    } else {
        #pragma unroll
        for (int k = 0; k < 4; ++k) if (base + k < N) c[k] = cnt[base + k];
    }
    int tsum = c[0] + c[1] + c[2] + c[3];
    sh[t] = tsum;
    __syncthreads();
    for (int d = 1; d < 256; d <<= 1) {
        int o = (t >= d) ? sh[t - d] : 0;
        __syncthreads();
        sh[t] += o;
        __syncthreads();
    }
    int run = sbase + sh[t] - tsum;
    #pragma unroll
    for (int k = 0; k < 4; ++k) {
        if (base + k < N) {
            offs[base + k] = run;
            dinv[base + k] = rsqrtf((float)c[k] + 1.0f);
            run += c[k];
        }
    }
    if (b == 0 && t == 0) offs[N] = E;
}

// fill edge records {src*64 (uint2 index), dinv[src]} grouped by dst
__global__ void fill_kernel(const int* __restrict__ src, const int* __restrict__ dst,
                            const int* __restrict__ offs, int* __restrict__ cur,
                            const float* __restrict__ dinv, int2* __restrict__ epack, int E) {
    int e = blockIdx.x * 256 + threadIdx.x;
    if (e < E) {
        int d = dst[e];
        int sv = src[e];
        int p = offs[d] + atomicAdd(&cur[d], 1);
        epack[p] = make_int2(sv * 64, __float_as_int(dinv[sv]));
    }
}

// ---------------- merged preprocessing ----------------

struct PrepArgs {
    const float *x, *s;
    const float *pre_w, *pre_b, *emb_w, *emb_b, *gin_w1, *gcn_w, *gin_w2;
    ushort *xs, *Wt_preemb, *Wt_dual, *Wt_gin2;
    float *bias_comb;
    int L, N;
};

__global__ void prep_kernel(PrepArgs a) {
    long idx = (long)blockIdx.x * 256 + threadIdx.x;
    long nconv = (long)a.N * 24;
    if (idx < nconv) {
        int n = (int)(idx / 24), ch = (int)(idx % 24);
        uint4 o = {0u, 0u, 0u, 0u};
        if (ch < 16) {
            const float4* px = (const float4*)(a.x + (long)n * 128 + ch * 8);
            float4 u = px[0], v = px[1];
            o.x = packbf(u.x, u.y); o.y = packbf(u.z, u.w);
            o.z = packbf(v.x, v.y); o.w = packbf(v.z, v.w);
        } else if (ch < 18) {
            const float4* ps = (const float4*)(a.s + (long)n * 16 + (ch - 16) * 8);
            float4 u = ps[0], v = ps[1];
            o.x = packbf(u.x, u.y); o.y = packbf(u.z, u.w);
            o.z = packbf(v.x, v.y); o.w = packbf(v.z, v.w);
        }
        *(uint4*)(a.xs + idx * 8) = o;
        return;
    }
    idx -= nconv;
    if (idx < 49152) {
        int c = (int)(idx / 192), k = (int)(idx % 192);
        float v = 0.f;
        if (c < 128) { if (k < 128) v = a.pre_w[(long)k * 128 + c]; }
        else if (k >= 128 && k < 144) v = a.emb_w[(long)(k - 128) * 128 + (c - 128)];
        a.Wt_preemb[idx] = f2bu(v);
        return;
    }
    idx -= 49152;
    if (idx < (long)a.L * 65536) {
        int i = (int)(idx / 65536);
        int r = (int)(idx % 65536);
        int c = r / 256, k = r % 256;
        float v = 0.f;
        if (c < 128) v = a.gin_w1[(long)i * 32768 + (long)k * 128 + c];
        else if (k >= 128) v = a.gcn_w[(long)i * 16384 + (long)(k - 128) * 128 + (c - 128)];
        a.Wt_dual[idx] = f2bu(v);
        return;
    }
    idx -= (long)a.L * 65536;
    if (idx < (long)a.L * 16384) {
        int i = (int)(idx / 16384);
        int r = (int)(idx % 16384);
        int c = r / 128, k = r % 128;
        a.Wt_gin2[idx] = f2bu(a.gin_w2[(long)i * 16384 + (long)k * 128 + c]);
        return;
    }
    idx -= (long)a.L * 16384;
    if (idx < 256) a.bias_comb[idx] = (idx < 128) ? a.pre_b[idx] : a.emb_b[idx - 128];
}

// ---------------- unified MFMA linear: BM=128, 8 waves, global_load_lds staging ----------------

template<int KPAD, int BN>
__global__ __launch_bounds__(512) void lin_mfma(
    const ushort* __restrict__ A, int a_stride,
    const ushort* __restrict__ Wt, const float* __restrict__ bias,
    ushort* __restrict__ out, int o_stride, int N, int act, int interleaved)
{
    constexpr int BK = 64;
    constexpr int NF = BN / 64;
    __shared__ __align__(16) ushort LA[128][BK];
    __shared__ __align__(16) ushort LB[BN][BK];

    const int tid  = threadIdx.x;
    const int l    = tid & 63;
    const int w    = tid >> 6;
    const int wr   = w >> 2;
    const int wc   = w & 3;
    const int row0 = blockIdx.x * 128;
    const int l15  = l & 15;
    const int lhi  = l >> 4;
    const int lrow = l >> 3;
    const int lslot = l & 7;

    f32x4 acc[4][NF];
    #pragma unroll
    for (int m = 0; m < 4; ++m)
        #pragma unroll
        for (int n = 0; n < NF; ++n) acc[m][n] = (f32x4){0.f, 0.f, 0.f, 0.f};

    for (int k0 = 0; k0 < KPAD; k0 += BK) {
        __syncthreads();
        #pragma unroll
        for (int i = 0; i < 2; ++i) {
            int ci = w * 2 + i;
            int r  = ci * 8 + lrow;
            int gr = row0 + r; if (gr > N - 1) gr = N - 1;
            gload16(A + (long)gr * a_stride + k0 + ((lslot ^ (r & 7)) * 8), &LA[ci * 8][0]);
        }
        #pragma unroll
        for (int i = 0; i < NF; ++i) {
            int ci = w * NF + i;
            int c  = ci * 8 + lrow;
            gload16(Wt + (long)c * KPAD + k0 + ((lslot ^ (c & 7)) * 8), &LB[ci * 8][0]);
        }
        __syncthreads();
        #pragma unroll
        for (int kk = 0; kk < BK; kk += 32) {
            int chb = (kk >> 3) + lhi;
            short8 a[4];
            #pragma unroll
            for (int m = 0; m < 4; ++m) {
                int r = wr * 64 + m * 16 + l15;
                a[m] = *(const short8*)&LA[r][(chb ^ (r & 7)) * 8];
            }
            #pragma unroll
            for (int n = 0; n < NF; ++n) {
                int c = wc * (BN / 4) + n * 16 + l15;
                short8 b = *(const short8*)&LB[c][(chb ^ (c & 7)) * 8];
                #pragma unroll
                for (int m = 0; m < 4; ++m)
                    acc[m][n] = __builtin_amdgcn_mfma_f32_16x16x32_bf16(a[m], b, acc[m][n], 0, 0, 0);
            }
        }
    }

    #pragma unroll
    for (int n = 0; n < NF; ++n) {
        int col = wc * (BN / 4) + n * 16 + l15;
        float bv = bias ? bias[col] : 0.f;
        #pragma unroll
        for (int m = 0; m < 4; ++m) {
            #pragma unroll
            for (int j = 0; j < 4; ++j) {
                int gr = row0 + wr * 64 + m * 16 + (lhi << 2) + j;
                if (gr < N) {
                    float v = acc[m][n][j] + bv;
                    if (act) v = fmaxf(v, 0.f);
                    long off;
                    if (interleaved) {
                        int cc = col & 127;
                        off = (long)gr * 256 + 4 * (cc >> 1) + ((col >> 7) << 1) + (cc & 1);
                    } else {
                        off = (long)gr * o_stride + col;
                    }
                    out[off] = f2bu(v);
                }
            }
        }
    }
}

// ---------------- fused GIN+GCN gather (scalar edge records, unroll-16 + masked-8 tail) ----------------
// 4 nodes/block, 256 thr. epack.x = src*64 (uint2 index), epack.y = dinv[src] bits.
// node/j0/j1 wave-uniform via readfirstlane -> epack batches are s_load (SGPR),
// leaving the vector pipe for the 16 in-flight random yh loads.

__global__ __launch_bounds__(256) void fused_gather(
    const uint2* __restrict__ yh, const int* __restrict__ offs,
    const int2* __restrict__ epack,
    const float* __restrict__ dinv,
    const float* __restrict__ b1, const float* __restrict__ gb,
    uint* __restrict__ h1p, uint* __restrict__ xcp, int N)
{
    int node = blockIdx.x * 4 + (threadIdx.x >> 6);
    if (node >= N) return;
    node = __builtin_amdgcn_readfirstlane(node);
    int l = threadIdx.x & 63;

    uint2 self = yh[(long)node * 64 + l];
    float di = dinv[node];
    float g0 = blo(self.x), g1 = bhi(self.x);
    float s0 = 0.f, s1 = 0.f;

    int j0 = __builtin_amdgcn_readfirstlane(offs[node]);
    int j1 = __builtin_amdgcn_readfirstlane(offs[node + 1]);
    int jmid = j0 + ((j1 - j0) & ~15);

    for (int j = j0; j < jmid; j += 16) {
        int2 e[16]; uint2 v[16];
        #pragma unroll
        for (int k = 0; k < 16; ++k) e[k] = epack[j + k];
        #pragma unroll
        for (int k = 0; k < 16; ++k) v[k] = yh[e[k].x + l];
        #pragma unroll
        for (int k = 0; k < 16; ++k) {
            float ds = __int_as_float(e[k].y);
            g0 += blo(v[k].x);
            g1 += bhi(v[k].x);
            s0 += blo(v[k].y) * ds;
            s1 += bhi(v[k].y) * ds;
        }
    }
    for (int j = jmid; j < j1; j += 8) {       // masked batches of 8 (0..2 iters)
        int2 e[8]; uint2 v[8];
        #pragma unroll
        for (int k = 0; k < 8; ++k) {
            int jj = j + k;
            e[k] = epack[(jj < j1) ? jj : (j1 - 1)];
            if (jj >= j1) e[k].y = 0;
        }
        #pragma unroll
        for (int k = 0; k < 8; ++k) v[k] = yh[e[k].x + l];
        #pragma unroll
        for (int k = 0; k < 8; ++k) {
            float ds = __int_as_float(e[k].y);
            float m = (j + k < j1) ? 1.f : 0.f;
            g0 += blo(v[k].x) * m;
            g1 += bhi(v[k].x) * m;
            s0 += blo(v[k].y) * ds;
            s1 += bhi(v[k].y) * ds;
        }
    }

    float2 bb = ((const float2*)b1)[l];
    g0 = fmaxf(g0 + bb.x, 0.f);
    g1 = fmaxf(g1 + bb.y, 0.f);
    h1p[(long)node * 64 + l] = packbf(g0, g1);

    float dii = di * di;
    float2 gg = ((const float2*)gb)[l];
    float t0 = tanhf(s0 * di + blo(self.y) * dii + gg.x);
    float t1 = tanhf(s1 * di + bhi(self.y) * dii + gg.y);
    xcp[(long)node * 128 + 64 + l] = packbf(t0, t1);
}

// ---------------- pooling: gsum[G][256] = sum over graph of xc rows; cntg = node counts ----------------
// Pooling before whp (linear): g = (sum xc) @ whp_w + cnt*whp_b computed in head.

__global__ void pool_kernel(const ushort* __restrict__ xc, const int* __restrict__ batch,
                            float* __restrict__ gsum, int* __restrict__ cntg, int N) {
    int c  = threadIdx.x;    // 256 channels
    int n0 = blockIdx.x * 128;
    if (n0 >= N) return;
    int n1 = min(n0 + 128, N);
    int curg = batch[n0];
    float acc = 0.f;
    int cnt = 0;
    for (int n = n0; n < n1; ++n) {
        int b = batch[n];
        if (b != curg) {
            atomicAdd(&gsum[(long)curg * 256 + c], acc);
            if (c == 0) atomicAdd(&cntg[curg], cnt);
            acc = 0.f; cnt = 0;
            curg = b;
        }
        acc += blo((uint)xc[(long)n * 256 + c]);
        cnt++;
    }
    atomicAdd(&gsum[(long)curg * 256 + c], acc);
    if (c == 0) atomicAdd(&cntg[curg], cnt);
}

// ---------------- head: whp + post + readout + log_softmax (G blocks x 128 thr) ----------------

__global__ void head_kernel(const float* __restrict__ gsum, const int* __restrict__ cntg,
                            const float* __restrict__ whp_w, const float* __restrict__ whp_b,
                            const float* __restrict__ post_w, const float* __restrict__ post_b,
                            const float* __restrict__ ro_w, const float* __restrict__ ro_b,
                            float* __restrict__ out, int C) {
    __shared__ float row[256];
    __shared__ float xr[128];
    __shared__ float g2[128];
    __shared__ float lg[16];
    __shared__ float s_lse;
    int gi = blockIdx.x;
    int c  = threadIdx.x;   // 128
    row[c]       = gsum[(long)gi * 256 + c];
    row[c + 128] = gsum[(long)gi * 256 + 128 + c];
    __syncthreads();
    float cntf = (float)cntg[gi];
    float acc = cntf * whp_b[c];
    for (int k = 0; k < 256; ++k) acc += row[k] * whp_w[(long)k * 128 + c];
    xr[c] = acc;
    __syncthreads();
    float a2 = post_b[c];
    for (int k = 0; k < 128; ++k) a2 += xr[k] * post_w[k * 128 + c];
    g2[c] = fmaxf(a2, 0.f);
    __syncthreads();
    if (c < C) {
        float a = ro_b[c];
        for (int k = 0; k < 128; ++k) a += g2[k] * ro_w[k * C + c];
        lg[c] = a;
    }
    __syncthreads();
    if (c == 0) {
        float m = lg[0];
        for (int i = 1; i < C; ++i) m = fmaxf(m, lg[i]);
        float sum = 0.f;
        for (int i = 0; i < C; ++i) sum += expf(lg[i] - m);
        s_lse = m + logf(sum);
    }
    __syncthreads();
    if (c < C) out[(long)gi * C + c] = lg[c] - s_lse;
}

// ---------------- launch ----------------

extern "C" void kernel_launch(void* const* d_in, const int* in_sizes, int n_in,
                              void* d_out, int out_size, void* d_ws, size_t ws_size,
                              hipStream_t stream) {
    const float* x      = (const float*)d_in[0];
    const float* s_in   = (const float*)d_in[1];
    const int*   ei     = (const int*)d_in[2];
    const int*   batch  = (const int*)d_in[3];
    const float* pre_w  = (const float*)d_in[4];
    const float* pre_b  = (const float*)d_in[5];
    const float* emb_w  = (const float*)d_in[6];
    const float* emb_b  = (const float*)d_in[7];
    const float* gin_w1 = (const float*)d_in[8];
    const float* gin_b1 = (const float*)d_in[9];
    const float* gin_w2 = (const float*)d_in[10];
    const float* gin_b2 = (const float*)d_in[11];
    const float* gcn_w  = (const float*)d_in[12];
    const float* gcn_b  = (const float*)d_in[13];
    const float* whp_w  = (const float*)d_in[14];
    const float* whp_b  = (const float*)d_in[15];
    const float* post_w = (const float*)d_in[16];
    const float* post_b = (const float*)d_in[17];
    const float* ro_w   = (const float*)d_in[18];
    const float* ro_b   = (const float*)d_in[19];

    const int H = 128;
    const int N = in_sizes[0] / 128;
    const int E = in_sizes[2] / 2;
    const int C = in_sizes[19];
    const int G = out_size / C;
    const int L = in_sizes[9] / H;

    const int* srcv = ei;
    const int* dstv = ei + E;

    char* p = (char*)d_ws;
    auto alloc = [&](size_t bytes) -> void* {
        void* r = (void*)p;
        p += (bytes + 255) & ~(size_t)255;
        return r;
    };
    ushort* xc   = (ushort*)alloc((size_t)N * 256 * 2);
    ushort* yh   = (ushort*)alloc((size_t)N * 256 * 2);
    ushort* h1   = (ushort*)alloc((size_t)N * 128 * 2);
    ushort* xs   = (ushort*)alloc((size_t)N * 192 * 2);
    ushort* Wt_preemb = (ushort*)alloc(256 * 192 * 2);
    ushort* Wt_dual   = (ushort*)alloc((size_t)L * 256 * 256 * 2);
    ushort* Wt_gin2   = (ushort*)alloc((size_t)L * 128 * 128 * 2);
    float*  bias_comb = (float*)alloc(256 * 4);
    float*  dinv = (float*)alloc((size_t)N * 4);
    float*  gsum = (float*)alloc((size_t)G * 256 * 4);
    int*    cntg = (int*)alloc((size_t)G * 4);
    int* cnt   = (int*)alloc((size_t)N * 4);
    int* offs  = (int*)alloc((size_t)(N + 1) * 4);
    int* cur   = (int*)alloc((size_t)N * 4);
    int* bsum  = (int*)alloc((size_t)HGRID(N, 1024) * 4);
    int2* epack = (int2*)alloc((size_t)E * 8);

    const int nb = HGRID(N, 1024);

    init_kernel<<<HGRID(max(N, G * 256), 256), 256, 0, stream>>>(cnt, cur, gsum, cntg,
                                                                 N, G * 256, G);
    count_kernel<<<HGRID(E, 256), 256, 0, stream>>>(dstv, cnt, E);
    scan_part<<<nb, 256, 0, stream>>>(cnt, bsum, N);
    scan_fill<<<nb, 256, 0, stream>>>(cnt, bsum, offs, dinv, N, E);
    fill_kernel<<<HGRID(E, 256), 256, 0, stream>>>(srcv, dstv, offs, cur, dinv, epack, E);

    PrepArgs pa;
    pa.x = x; pa.s = s_in;
    pa.pre_w = pre_w; pa.pre_b = pre_b; pa.emb_w = emb_w; pa.emb_b = emb_b;
    pa.gin_w1 = gin_w1; pa.gcn_w = gcn_w; pa.gin_w2 = gin_w2;
    pa.xs = xs; pa.Wt_preemb = Wt_preemb; pa.Wt_dual = Wt_dual; pa.Wt_gin2 = Wt_gin2;
    pa.bias_comb = bias_comb; pa.L = L; pa.N = N;
    long prep_tot = (long)N * 24 + 49152 + (long)L * 65536 + (long)L * 16384 + 256;
    prep_kernel<<<HGRID(prep_tot, 256), 256, 0, stream>>>(pa);

    const int lb = HGRID(N, 128);
    lin_mfma<192, 256><<<lb, 512, 0, stream>>>(xs, 192, Wt_preemb, bias_comb,
                                               xc, 256, N, 0, 0);

    for (int i = 0; i < L; ++i) {
        lin_mfma<256, 256><<<lb, 512, 0, stream>>>(xc, 256, Wt_dual + (size_t)i * 65536,
                                                   nullptr, yh, 256, N, 0, 1);
        fused_gather<<<HGRID(N, 4), 256, 0, stream>>>(
            (const uint2*)yh, offs, epack, dinv,
            gin_b1 + (size_t)i * H, gcn_b + (size_t)i * H,
            (uint*)h1, (uint*)xc, N);
        lin_mfma<128, 128><<<lb, 512, 0, stream>>>(h1, 128, Wt_gin2 + (size_t)i * 16384,
                                                   gin_b2 + (size_t)i * H, xc, 256, N, 1, 0);
    }

    pool_kernel<<<HGRID(N, 128), 256, 0, stream>>>(xc, batch, gsum, cntg, N);
    head_kernel<<<G, 128, 0, stream>>>(gsum, cntg, whp_w, whp_b,
                                       post_w, post_b, ro_w, ro_b, (float*)d_out, C);
}

// Round 12
// 394.712 us; speedup vs baseline: 1.3500x; 1.0732x over previous
//
#include <hip/hip_runtime.h>
#include <math.h>

typedef __attribute__((ext_vector_type(8))) short short8;
typedef __attribute__((ext_vector_type(4))) float f32x4;
typedef unsigned int uint;
typedef unsigned short ushort;

#define HGRID(n, b) (((n) + (b) - 1) / (b))

__device__ __forceinline__ ushort f2bu(float f) {
    uint x = __builtin_bit_cast(uint, f);
    x = (x + 0x7fffu + ((x >> 16) & 1u)) >> 16;
    return (ushort)x;
}
__device__ __forceinline__ float blo(uint u) {   // low bf16 half -> float
    return __builtin_bit_cast(float, u << 16);
}
__device__ __forceinline__ float bhi(uint u) {   // high bf16 half -> float
    return __builtin_bit_cast(float, u & 0xffff0000u);
}
__device__ __forceinline__ uint packbf(float a, float b) {
    return (uint)f2bu(a) | ((uint)f2bu(b) << 16);
}

// async global->LDS, 16 B per lane; LDS dest = wave-uniform base + lane*16
__device__ __forceinline__ void gload16(const void* g, void* l) {
    __builtin_amdgcn_global_load_lds(
        (const __attribute__((address_space(1))) void*)g,
        (__attribute__((address_space(3))) void*)l, 16, 0, 0);
}

// ---------------- CSR build ----------------

// rank[e] = position of edge e within its dst group (atomic return value)
__global__ void count_kernel(const int* __restrict__ dst, int* __restrict__ cnt,
                             int* __restrict__ rank, int E) {
    int e = blockIdx.x * 256 + threadIdx.x;
    if (e < E) rank[e] = atomicAdd(&cnt[dst[e]], 1);
}

__global__ void scan_part(const int* __restrict__ cnt, int* __restrict__ bsum, int N) {
    __shared__ int sh[256];
    int b = blockIdx.x, t = threadIdx.x;
    int base = b * 1024 + t * 4;
    int tsum = 0;
    if (base + 3 < N) {
        int4 v = *(const int4*)(cnt + base);
        tsum = v.x + v.y + v.z + v.w;
    } else {
        #pragma unroll
        for (int k = 0; k < 4; ++k) if (base + k < N) tsum += cnt[base + k];
    }
    sh[t] = tsum;
    __syncthreads();
    for (int d = 128; d > 0; d >>= 1) {
        if (t < d) sh[t] += sh[t + d];
        __syncthreads();
    }
    if (t == 0) bsum[b] = sh[0];
}

__global__ void scan_fill(const int* __restrict__ cnt, const int* __restrict__ bsum,
                          int* __restrict__ offs, float* __restrict__ dinv,
                          int N, int E) {
    __shared__ int sh[256];
    __shared__ int sbase;
    int b = blockIdx.x, t = threadIdx.x;

    if (t < 64) {
        int s = 0;
        for (int i = t; i < b; i += 64) s += bsum[i];
        #pragma unroll
        for (int d = 32; d > 0; d >>= 1) s += __shfl_down(s, d, 64);
        if (t == 0) sbase = s;
    }

    int base = b * 1024 + t * 4;
    int c[4] = {0, 0, 0, 0};
    if (base + 3 < N) {
        int4 v = *(const int4*)(cnt + base);
        c[0] = v.x; c[1] = v.y; c[2] = v.z; c[3] = v.w;
    } else {
        #pragma unroll
        for (int k = 0; k < 4; ++k) if (base + k < N) c[k] = cnt[base + k];
    }
    int tsum = c[0] + c[1] + c[2] + c[3];
    sh[t] = tsum;
    __syncthreads();
    for (int d = 1; d < 256; d <<= 1) {
        int o = (t >= d) ? sh[t - d] : 0;
        __syncthreads();
        sh[t] += o;
        __syncthreads();
    }
    int run = sbase + sh[t] - tsum;
    #pragma unroll
    for (int k = 0; k < 4; ++k) {
        if (base + k < N) {
            offs[base + k] = run;
            dinv[base + k] = rsqrtf((float)c[k] + 1.0f);
            run += c[k];
        }
    }
    if (b == 0 && t == 0) offs[N] = E;
}

// fill edge records {src*64 (uint2 index), dinv[src]} grouped by dst; no atomics
__global__ void fill_kernel(const int* __restrict__ src, const int* __restrict__ dst,
                            const int* __restrict__ offs, const int* __restrict__ rank,
                            const float* __restrict__ dinv, int2* __restrict__ epack, int E) {
    int e = blockIdx.x * 256 + threadIdx.x;
    if (e < E) {
        int d = dst[e];
        int sv = src[e];
        epack[offs[d] + rank[e]] = make_int2(sv * 64, __float_as_int(dinv[sv]));
    }
}

// ---------------- merged setup: conversion + weight transposes + bias + zero-init ----------------

struct SetupArgs {
    const float *x, *s;
    const float *pre_w, *pre_b, *emb_w, *emb_b, *gin_w1, *gcn_w, *gin_w2;
    ushort *xs, *Wt_preemb, *Wt_dual, *Wt_gin2;
    float *bias_comb;
    int *cnt; float *gsum; int *cntg;
    int L, N, G;
};

__global__ void setup_kernel(SetupArgs a) {
    long idx = (long)blockIdx.x * 256 + threadIdx.x;
    long nconv = (long)a.N * 24;
    if (idx < nconv) {
        int n = (int)(idx / 24), ch = (int)(idx % 24);
        uint4 o = {0u, 0u, 0u, 0u};
        if (ch < 16) {
            const float4* px = (const float4*)(a.x + (long)n * 128 + ch * 8);
            float4 u = px[0], v = px[1];
            o.x = packbf(u.x, u.y); o.y = packbf(u.z, u.w);
            o.z = packbf(v.x, v.y); o.w = packbf(v.z, v.w);
        } else if (ch < 18) {
            const float4* ps = (const float4*)(a.s + (long)n * 16 + (ch - 16) * 8);
            float4 u = ps[0], v = ps[1];
            o.x = packbf(u.x, u.y); o.y = packbf(u.z, u.w);
            o.z = packbf(v.x, v.y); o.w = packbf(v.z, v.w);
        }
        *(uint4*)(a.xs + idx * 8) = o;
        return;
    }
    idx -= nconv;
    if (idx < 49152) {
        int c = (int)(idx / 192), k = (int)(idx % 192);
        float v = 0.f;
        if (c < 128) { if (k < 128) v = a.pre_w[(long)k * 128 + c]; }
        else if (k >= 128 && k < 144) v = a.emb_w[(long)(k - 128) * 128 + (c - 128)];
        a.Wt_preemb[idx] = f2bu(v);
        return;
    }
    idx -= 49152;
    if (idx < (long)a.L * 65536) {
        int i = (int)(idx / 65536);
        int r = (int)(idx % 65536);
        int c = r / 256, k = r % 256;
        float v = 0.f;
        if (c < 128) v = a.gin_w1[(long)i * 32768 + (long)k * 128 + c];
        else if (k >= 128) v = a.gcn_w[(long)i * 16384 + (long)(k - 128) * 128 + (c - 128)];
        a.Wt_dual[idx] = f2bu(v);
        return;
    }
    idx -= (long)a.L * 65536;
    if (idx < (long)a.L * 16384) {
        int i = (int)(idx / 16384);
        int r = (int)(idx % 16384);
        int c = r / 128, k = r % 128;
        a.Wt_gin2[idx] = f2bu(a.gin_w2[(long)i * 16384 + (long)k * 128 + c]);
        return;
    }
    idx -= (long)a.L * 16384;
    if (idx < 256) { a.bias_comb[idx] = (idx < 128) ? a.pre_b[idx] : a.emb_b[idx - 128]; return; }
    idx -= 256;
    if (idx < a.N) { a.cnt[idx] = 0; return; }
    idx -= a.N;
    if (idx < (long)a.G * 256) { a.gsum[idx] = 0.f; return; }
    idx -= (long)a.G * 256;
    if (idx < a.G) a.cntg[idx] = 0;
}

// ---------------- unified MFMA linear: BM=128, 8 waves, global_load_lds staging ----------------

template<int KPAD, int BN>
__global__ __launch_bounds__(512) void lin_mfma(
    const ushort* __restrict__ A, int a_stride,
    const ushort* __restrict__ Wt, const float* __restrict__ bias,
    ushort* __restrict__ out, int o_stride, int N, int act, int interleaved)
{
    constexpr int BK = 64;
    constexpr int NF = BN / 64;
    __shared__ __align__(16) ushort LA[128][BK];
    __shared__ __align__(16) ushort LB[BN][BK];

    const int tid  = threadIdx.x;
    const int l    = tid & 63;
    const int w    = tid >> 6;
    const int wr   = w >> 2;
    const int wc   = w & 3;
    const int row0 = blockIdx.x * 128;
    const int l15  = l & 15;
    const int lhi  = l >> 4;
    const int lrow = l >> 3;
    const int lslot = l & 7;

    f32x4 acc[4][NF];
    #pragma unroll
    for (int m = 0; m < 4; ++m)
        #pragma unroll
        for (int n = 0; n < NF; ++n) acc[m][n] = (f32x4){0.f, 0.f, 0.f, 0.f};

    for (int k0 = 0; k0 < KPAD; k0 += BK) {
        __syncthreads();
        #pragma unroll
        for (int i = 0; i < 2; ++i) {
            int ci = w * 2 + i;
            int r  = ci * 8 + lrow;
            int gr = row0 + r; if (gr > N - 1) gr = N - 1;
            gload16(A + (long)gr * a_stride + k0 + ((lslot ^ (r & 7)) * 8), &LA[ci * 8][0]);
        }
        #pragma unroll
        for (int i = 0; i < NF; ++i) {
            int ci = w * NF + i;
            int c  = ci * 8 + lrow;
            gload16(Wt + (long)c * KPAD + k0 + ((lslot ^ (c & 7)) * 8), &LB[ci * 8][0]);
        }
        __syncthreads();
        #pragma unroll
        for (int kk = 0; kk < BK; kk += 32) {
            int chb = (kk >> 3) + lhi;
            short8 a[4];
            #pragma unroll
            for (int m = 0; m < 4; ++m) {
                int r = wr * 64 + m * 16 + l15;
                a[m] = *(const short8*)&LA[r][(chb ^ (r & 7)) * 8];
            }
            #pragma unroll
            for (int n = 0; n < NF; ++n) {
                int c = wc * (BN / 4) + n * 16 + l15;
                short8 b = *(const short8*)&LB[c][(chb ^ (c & 7)) * 8];
                #pragma unroll
                for (int m = 0; m < 4; ++m)
                    acc[m][n] = __builtin_amdgcn_mfma_f32_16x16x32_bf16(a[m], b, acc[m][n], 0, 0, 0);
            }
        }
    }

    #pragma unroll
    for (int n = 0; n < NF; ++n) {
        int col = wc * (BN / 4) + n * 16 + l15;
        float bv = bias ? bias[col] : 0.f;
        #pragma unroll
        for (int m = 0; m < 4; ++m) {
            #pragma unroll
            for (int j = 0; j < 4; ++j) {
                int gr = row0 + wr * 64 + m * 16 + (lhi << 2) + j;
                if (gr < N) {
                    float v = acc[m][n][j] + bv;
                    if (act) v = fmaxf(v, 0.f);
                    long off;
                    if (interleaved) {
                        int cc = col & 127;
                        off = (long)gr * 256 + 4 * (cc >> 1) + ((col >> 7) << 1) + (cc & 1);
                    } else {
                        off = (long)gr * o_stride + col;
                    }
                    out[off] = f2bu(v);
                }
            }
        }
    }
}

// ---------------- fused GIN+GCN gather (scalar edge records, unroll-16 + masked-4 tail) ----------------
// 4 nodes/block, 256 thr. epack.x = src*64 (uint2 index), epack.y = dinv[src] bits.
// node/j0/j1 wave-uniform via readfirstlane -> epack batches are s_load (SGPR).

__global__ __launch_bounds__(256) void fused_gather(
    const uint2* __restrict__ yh, const int* __restrict__ offs,
    const int2* __restrict__ epack,
    const float* __restrict__ dinv,
    const float* __restrict__ b1, const float* __restrict__ gb,
    uint* __restrict__ h1p, uint* __restrict__ xcp, int N)
{
    int node = blockIdx.x * 4 + (threadIdx.x >> 6);
    if (node >= N) return;
    node = __builtin_amdgcn_readfirstlane(node);
    int l = threadIdx.x & 63;

    uint2 self = yh[(long)node * 64 + l];
    float di = dinv[node];
    float g0 = blo(self.x), g1 = bhi(self.x);
    float s0 = 0.f, s1 = 0.f;

    int j0 = __builtin_amdgcn_readfirstlane(offs[node]);
    int j1 = __builtin_amdgcn_readfirstlane(offs[node + 1]);
    int jmid = j0 + ((j1 - j0) & ~15);

    for (int j = j0; j < jmid; j += 16) {
        int2 e[16]; uint2 v[16];
        #pragma unroll
        for (int k = 0; k < 16; ++k) e[k] = epack[j + k];
        #pragma unroll
        for (int k = 0; k < 16; ++k) v[k] = yh[e[k].x + l];
        #pragma unroll
        for (int k = 0; k < 16; ++k) {
            float ds = __int_as_float(e[k].y);
            g0 += blo(v[k].x);
            g1 += bhi(v[k].x);
            s0 += blo(v[k].y) * ds;
            s1 += bhi(v[k].y) * ds;
        }
    }
    for (int j = jmid; j < j1; j += 4) {       // masked batches of 4 (0..4 iters)
        int2 e[4]; uint2 v[4];
        #pragma unroll
        for (int k = 0; k < 4; ++k) {
            int jj = j + k;
            e[k] = epack[(jj < j1) ? jj : (j1 - 1)];
            if (jj >= j1) e[k].y = 0;
        }
        #pragma unroll
        for (int k = 0; k < 4; ++k) v[k] = yh[e[k].x + l];
        #pragma unroll
        for (int k = 0; k < 4; ++k) {
            float ds = __int_as_float(e[k].y);
            float m = (j + k < j1) ? 1.f : 0.f;
            g0 += blo(v[k].x) * m;
            g1 += bhi(v[k].x) * m;
            s0 += blo(v[k].y) * ds;
            s1 += bhi(v[k].y) * ds;
        }
    }

    float2 bb = ((const float2*)b1)[l];
    g0 = fmaxf(g0 + bb.x, 0.f);
    g1 = fmaxf(g1 + bb.y, 0.f);
    h1p[(long)node * 64 + l] = packbf(g0, g1);

    float dii = di * di;
    float2 gg = ((const float2*)gb)[l];
    float t0 = tanhf(s0 * di + blo(self.y) * dii + gg.x);
    float t1 = tanhf(s1 * di + bhi(self.y) * dii + gg.y);
    xcp[(long)node * 128 + 64 + l] = packbf(t0, t1);
}

// ---------------- pooling: gsum[G][256] = per-graph sum of xc rows; cntg = node counts ----------------

__global__ void pool_kernel(const ushort* __restrict__ xc, const int* __restrict__ batch,
                            float* __restrict__ gsum, int* __restrict__ cntg, int N) {
    int c  = threadIdx.x;    // 256 channels
    int n0 = blockIdx.x * 128;
    if (n0 >= N) return;
    int n1 = min(n0 + 128, N);
    int curg = batch[n0];
    float acc = 0.f;
    int cnt = 0;
    for (int n = n0; n < n1; ++n) {
        int b = batch[n];
        if (b != curg) {
            atomicAdd(&gsum[(long)curg * 256 + c], acc);
            if (c == 0) atomicAdd(&cntg[curg], cnt);
            acc = 0.f; cnt = 0;
            curg = b;
        }
        acc += blo((uint)xc[(long)n * 256 + c]);
        cnt++;
    }
    atomicAdd(&gsum[(long)curg * 256 + c], acc);
    if (c == 0) atomicAdd(&cntg[curg], cnt);
}

// ---------------- head: whp + post + readout + log_softmax ----------------

__global__ void head_kernel(const float* __restrict__ gsum, const int* __restrict__ cntg,
                            const float* __restrict__ whp_w, const float* __restrict__ whp_b,
                            const float* __restrict__ post_w, const float* __restrict__ post_b,
                            const float* __restrict__ ro_w, const float* __restrict__ ro_b,
                            float* __restrict__ out, int C) {
    __shared__ float row[256];
    __shared__ float xr[128];
    __shared__ float g2[128];
    __shared__ float lg[16];
    __shared__ float s_lse;
    int gi = blockIdx.x;
    int c  = threadIdx.x;   // 128
    row[c]       = gsum[(long)gi * 256 + c];
    row[c + 128] = gsum[(long)gi * 256 + 128 + c];
    __syncthreads();
    float cntf = (float)cntg[gi];
    float acc = cntf * whp_b[c];
    for (int k = 0; k < 256; ++k) acc += row[k] * whp_w[(long)k * 128 + c];
    xr[c] = acc;
    __syncthreads();
    float a2 = post_b[c];
    for (int k = 0; k < 128; ++k) a2 += xr[k] * post_w[k * 128 + c];
    g2[c] = fmaxf(a2, 0.f);
    __syncthreads();
    if (c < C) {
        float a = ro_b[c];
        for (int k = 0; k < 128; ++k) a += g2[k] * ro_w[k * C + c];
        lg[c] = a;
    }
    __syncthreads();
    if (c == 0) {
        float m = lg[0];
        for (int i = 1; i < C; ++i) m = fmaxf(m, lg[i]);
        float sum = 0.f;
        for (int i = 0; i < C; ++i) sum += expf(lg[i] - m);
        s_lse = m + logf(sum);
    }
    __syncthreads();
    if (c < C) out[(long)gi * C + c] = lg[c] - s_lse;
}

// ---------------- launch ----------------

extern "C" void kernel_launch(void* const* d_in, const int* in_sizes, int n_in,
                              void* d_out, int out_size, void* d_ws, size_t ws_size,
                              hipStream_t stream) {
    const float* x      = (const float*)d_in[0];
    const float* s_in   = (const float*)d_in[1];
    const int*   ei     = (const int*)d_in[2];
    const int*   batch  = (const int*)d_in[3];
    const float* pre_w  = (const float*)d_in[4];
    const float* pre_b  = (const float*)d_in[5];
    const float* emb_w  = (const float*)d_in[6];
    const float* emb_b  = (const float*)d_in[7];
    const float* gin_w1 = (const float*)d_in[8];
    const float* gin_b1 = (const float*)d_in[9];
    const float* gin_w2 = (const float*)d_in[10];
    const float* gin_b2 = (const float*)d_in[11];
    const float* gcn_w  = (const float*)d_in[12];
    const float* gcn_b  = (const float*)d_in[13];
    const float* whp_w  = (const float*)d_in[14];
    const float* whp_b  = (const float*)d_in[15];
    const float* post_w = (const float*)d_in[16];
    const float* post_b = (const float*)d_in[17];
    const float* ro_w   = (const float*)d_in[18];
    const float* ro_b   = (const float*)d_in[19];

    const int H = 128;
    const int N = in_sizes[0] / 128;
    const int E = in_sizes[2] / 2;
    const int C = in_sizes[19];
    const int G = out_size / C;
    const int L = in_sizes[9] / H;

    const int* srcv = ei;
    const int* dstv = ei + E;

    char* p = (char*)d_ws;
    auto alloc = [&](size_t bytes) -> void* {
        void* r = (void*)p;
        p += (bytes + 255) & ~(size_t)255;
        return r;
    };
    ushort* xc   = (ushort*)alloc((size_t)N * 256 * 2);
    ushort* yh   = (ushort*)alloc((size_t)N * 256 * 2);
    ushort* h1   = (ushort*)alloc((size_t)N * 128 * 2);
    ushort* xs   = (ushort*)alloc((size_t)N * 192 * 2);
    ushort* Wt_preemb = (ushort*)alloc(256 * 192 * 2);
    ushort* Wt_dual   = (ushort*)alloc((size_t)L * 256 * 256 * 2);
    ushort* Wt_gin2   = (ushort*)alloc((size_t)L * 128 * 128 * 2);
    float*  bias_comb = (float*)alloc(256 * 4);
    float*  dinv = (float*)alloc((size_t)N * 4);
    float*  gsum = (float*)alloc((size_t)G * 256 * 4);
    int*    cntg = (int*)alloc((size_t)G * 4);
    int* cnt   = (int*)alloc((size_t)N * 4);
    int* offs  = (int*)alloc((size_t)(N + 1) * 4);
    int* rank  = (int*)alloc((size_t)E * 4);
    int* bsum  = (int*)alloc((size_t)HGRID(N, 1024) * 4);
    int2* epack = (int2*)alloc((size_t)E * 8);

    const int nb = HGRID(N, 1024);

    SetupArgs sa;
    sa.x = x; sa.s = s_in;
    sa.pre_w = pre_w; sa.pre_b = pre_b; sa.emb_w = emb_w; sa.emb_b = emb_b;
    sa.gin_w1 = gin_w1; sa.gcn_w = gcn_w; sa.gin_w2 = gin_w2;
    sa.xs = xs; sa.Wt_preemb = Wt_preemb; sa.Wt_dual = Wt_dual; sa.Wt_gin2 = Wt_gin2;
    sa.bias_comb = bias_comb; sa.cnt = cnt; sa.gsum = gsum; sa.cntg = cntg;
    sa.L = L; sa.N = N; sa.G = G;
    long setup_tot = (long)N * 24 + 49152 + (long)L * 65536 + (long)L * 16384 + 256
                   + N + (long)G * 256 + G;
    setup_kernel<<<HGRID(setup_tot, 256), 256, 0, stream>>>(sa);

    count_kernel<<<HGRID(E, 256), 256, 0, stream>>>(dstv, cnt, rank, E);
    scan_part<<<nb, 256, 0, stream>>>(cnt, bsum, N);
    scan_fill<<<nb, 256, 0, stream>>>(cnt, bsum, offs, dinv, N, E);
    fill_kernel<<<HGRID(E, 256), 256, 0, stream>>>(srcv, dstv, offs, rank, dinv, epack, E);

    const int lb = HGRID(N, 128);
    lin_mfma<192, 256><<<lb, 512, 0, stream>>>(xs, 192, Wt_preemb, bias_comb,
                                               xc, 256, N, 0, 0);

    for (int i = 0; i < L; ++i) {
        lin_mfma<256, 256><<<lb, 512, 0, stream>>>(xc, 256, Wt_dual + (size_t)i * 65536,
                                                   nullptr, yh, 256, N, 0, 1);
        fused_gather<<<HGRID(N, 4), 256, 0, stream>>>(
            (const uint2*)yh, offs, epack, dinv,
            gin_b1 + (size_t)i * H, gcn_b + (size_t)i * H,
            (uint*)h1, (uint*)xc, N);
        lin_mfma<128, 128><<<lb, 512, 0, stream>>>(h1, 128, Wt_gin2 + (size_t)i * 16384,
                                                   gin_b2 + (size_t)i * H, xc, 256, N, 1, 0);
    }

    pool_kernel<<<HGRID(N, 128), 256, 0, stream>>>(xc, batch, gsum, cntg, N);
    head_kernel<<<G, 128, 0, stream>>>(gsum, cntg, whp_w, whp_b,
                                       post_w, post_b, ro_w, ro_b, (float*)d_out, C);
}

// Round 13
// 377.782 us; speedup vs baseline: 1.4105x; 1.0448x over previous
//
#include <hip/hip_runtime.h>
#include <math.h>

typedef __attribute__((ext_vector_type(8))) short short8;
typedef __attribute__((ext_vector_type(4))) float f32x4;
typedef unsigned int uint;
typedef unsigned short ushort;

#define HGRID(n, b) (((n) + (b) - 1) / (b))

__device__ __forceinline__ ushort f2bu(float f) {
    uint x = __builtin_bit_cast(uint, f);
    x = (x + 0x7fffu + ((x >> 16) & 1u)) >> 16;
    return (ushort)x;
}
__device__ __forceinline__ float blo(uint u) {   // low bf16 half -> float
    return __builtin_bit_cast(float, u << 16);
}
__device__ __forceinline__ float bhi(uint u) {   // high bf16 half -> float
    return __builtin_bit_cast(float, u & 0xffff0000u);
}
__device__ __forceinline__ uint packbf(float a, float b) {
    return (uint)f2bu(a) | ((uint)f2bu(b) << 16);
}

// async global->LDS, 16 B per lane; LDS dest = wave-uniform base + lane*16
__device__ __forceinline__ void gload16(const void* g, void* l) {
    __builtin_amdgcn_global_load_lds(
        (const __attribute__((address_space(1))) void*)g,
        (__attribute__((address_space(3))) void*)l, 16, 0, 0);
}

// ---------------- CSR build ----------------

// rank[e] = position of edge e within its dst group (atomic return value)
__global__ void count_kernel(const int* __restrict__ dst, int* __restrict__ cnt,
                             int* __restrict__ rank, int E) {
    int e = blockIdx.x * 256 + threadIdx.x;
    if (e < E) rank[e] = atomicAdd(&cnt[dst[e]], 1);
}

__global__ void scan_part(const int* __restrict__ cnt, int* __restrict__ bsum, int N) {
    __shared__ int sh[256];
    int b = blockIdx.x, t = threadIdx.x;
    int base = b * 1024 + t * 4;
    int tsum = 0;
    if (base + 3 < N) {
        int4 v = *(const int4*)(cnt + base);
        tsum = v.x + v.y + v.z + v.w;
    } else {
        #pragma unroll
        for (int k = 0; k < 4; ++k) if (base + k < N) tsum += cnt[base + k];
    }
    sh[t] = tsum;
    __syncthreads();
    for (int d = 128; d > 0; d >>= 1) {
        if (t < d) sh[t] += sh[t + d];
        __syncthreads();
    }
    if (t == 0) bsum[b] = sh[0];
}

__global__ void scan_fill(const int* __restrict__ cnt, const int* __restrict__ bsum,
                          int* __restrict__ offs, float* __restrict__ dinv,
                          int N, int E) {
    __shared__ int sh[256];
    __shared__ int sbase;
    int b = blockIdx.x, t = threadIdx.x;

    if (t < 64) {
        int s = 0;
        for (int i = t; i < b; i += 64) s += bsum[i];
        #pragma unroll
        for (int d = 32; d > 0; d >>= 1) s += __shfl_down(s, d, 64);
        if (t == 0) sbase = s;
    }

    int base = b * 1024 + t * 4;
    int c[4] = {0, 0, 0, 0};
    if (base + 3 < N) {
        int4 v = *(const int4*)(cnt + base);
        c[0] = v.x; c[1] = v.y; c[2] = v.z; c[3] = v.w;
    } else {
        #pragma unroll
        for (int k = 0; k < 4; ++k) if (base + k < N) c[k] = cnt[base + k];
    }
    int tsum = c[0] + c[1] + c[2] + c[3];
    sh[t] = tsum;
    __syncthreads();
    for (int d = 1; d < 256; d <<= 1) {
        int o = (t >= d) ? sh[t - d] : 0;
        __syncthreads();
        sh[t] += o;
        __syncthreads();
    }
    int run = sbase + sh[t] - tsum;
    #pragma unroll
    for (int k = 0; k < 4; ++k) {
        if (base + k < N) {
            offs[base + k] = run;
            dinv[base + k] = rsqrtf((float)c[k] + 1.0f);
            run += c[k];
        }
    }
    if (b == 0 && t == 0) offs[N] = E;
}

// fill edge records {src*64 (uint2 index), dinv[src]} grouped by dst; no atomics
__global__ void fill_kernel(const int* __restrict__ src, const int* __restrict__ dst,
                            const int* __restrict__ offs, const int* __restrict__ rank,
                            const float* __restrict__ dinv, int2* __restrict__ epack, int E) {
    int e = blockIdx.x * 256 + threadIdx.x;
    if (e < E) {
        int d = dst[e];
        int sv = src[e];
        epack[offs[d] + rank[e]] = make_int2(sv * 64, __float_as_int(dinv[sv]));
    }
}

// ---------------- merged setup: conversion + weight transposes + bias + zero-init ----------------

struct SetupArgs {
    const float *x, *s;
    const float *pre_w, *pre_b, *emb_w, *emb_b, *gin_w1, *gcn_w, *gin_w2;
    ushort *xs, *Wt_preemb, *Wt_dual, *Wt_gin2;
    float *bias_comb;
    int *cnt; float *gsum; int *cntg;
    int L, N, G;
};

__global__ void setup_kernel(SetupArgs a) {
    long idx = (long)blockIdx.x * 256 + threadIdx.x;
    long nconv = (long)a.N * 24;
    if (idx < nconv) {
        int n = (int)(idx / 24), ch = (int)(idx % 24);
        uint4 o = {0u, 0u, 0u, 0u};
        if (ch < 16) {
            const float4* px = (const float4*)(a.x + (long)n * 128 + ch * 8);
            float4 u = px[0], v = px[1];
            o.x = packbf(u.x, u.y); o.y = packbf(u.z, u.w);
            o.z = packbf(v.x, v.y); o.w = packbf(v.z, v.w);
        } else if (ch < 18) {
            const float4* ps = (const float4*)(a.s + (long)n * 16 + (ch - 16) * 8);
            float4 u = ps[0], v = ps[1];
            o.x = packbf(u.x, u.y); o.y = packbf(u.z, u.w);
            o.z = packbf(v.x, v.y); o.w = packbf(v.z, v.w);
        }
        *(uint4*)(a.xs + idx * 8) = o;
        return;
    }
    idx -= nconv;
    if (idx < 49152) {
        int c = (int)(idx / 192), k = (int)(idx % 192);
        float v = 0.f;
        if (c < 128) { if (k < 128) v = a.pre_w[(long)k * 128 + c]; }
        else if (k >= 128 && k < 144) v = a.emb_w[(long)(k - 128) * 128 + (c - 128)];
        a.Wt_preemb[idx] = f2bu(v);
        return;
    }
    idx -= 49152;
    if (idx < (long)a.L * 65536) {
        int i = (int)(idx / 65536);
        int r = (int)(idx % 65536);
        int c = r / 256, k = r % 256;
        float v = 0.f;
        if (c < 128) v = a.gin_w1[(long)i * 32768 + (long)k * 128 + c];
        else if (k >= 128) v = a.gcn_w[(long)i * 16384 + (long)(k - 128) * 128 + (c - 128)];
        a.Wt_dual[idx] = f2bu(v);
        return;
    }
    idx -= (long)a.L * 65536;
    if (idx < (long)a.L * 16384) {
        int i = (int)(idx / 16384);
        int r = (int)(idx % 16384);
        int c = r / 128, k = r % 128;
        a.Wt_gin2[idx] = f2bu(a.gin_w2[(long)i * 16384 + (long)k * 128 + c]);
        return;
    }
    idx -= (long)a.L * 16384;
    if (idx < 256) { a.bias_comb[idx] = (idx < 128) ? a.pre_b[idx] : a.emb_b[idx - 128]; return; }
    idx -= 256;
    if (idx < a.N) { a.cnt[idx] = 0; return; }
    idx -= a.N;
    if (idx < (long)a.G * 256) { a.gsum[idx] = 0.f; return; }
    idx -= (long)a.G * 256;
    if (idx < a.G) a.cntg[idx] = 0;
}

// ---------------- unified MFMA linear: BM=128, 8 waves, global_load_lds staging ----------------

template<int KPAD, int BN>
__global__ __launch_bounds__(512) void lin_mfma(
    const ushort* __restrict__ A, int a_stride,
    const ushort* __restrict__ Wt, const float* __restrict__ bias,
    ushort* __restrict__ out, int o_stride, int N, int act, int interleaved)
{
    constexpr int BK = 64;
    constexpr int NF = BN / 64;
    __shared__ __align__(16) ushort LA[128][BK];
    __shared__ __align__(16) ushort LB[BN][BK];

    const int tid  = threadIdx.x;
    const int l    = tid & 63;
    const int w    = tid >> 6;
    const int wr   = w >> 2;
    const int wc   = w & 3;
    const int row0 = blockIdx.x * 128;
    const int l15  = l & 15;
    const int lhi  = l >> 4;
    const int lrow = l >> 3;
    const int lslot = l & 7;

    f32x4 acc[4][NF];
    #pragma unroll
    for (int m = 0; m < 4; ++m)
        #pragma unroll
        for (int n = 0; n < NF; ++n) acc[m][n] = (f32x4){0.f, 0.f, 0.f, 0.f};

    for (int k0 = 0; k0 < KPAD; k0 += BK) {
        __syncthreads();
        #pragma unroll
        for (int i = 0; i < 2; ++i) {
            int ci = w * 2 + i;
            int r  = ci * 8 + lrow;
            int gr = row0 + r; if (gr > N - 1) gr = N - 1;
            gload16(A + (long)gr * a_stride + k0 + ((lslot ^ (r & 7)) * 8), &LA[ci * 8][0]);
        }
        #pragma unroll
        for (int i = 0; i < NF; ++i) {
            int ci = w * NF + i;
            int c  = ci * 8 + lrow;
            gload16(Wt + (long)c * KPAD + k0 + ((lslot ^ (c & 7)) * 8), &LB[ci * 8][0]);
        }
        __syncthreads();
        #pragma unroll
        for (int kk = 0; kk < BK; kk += 32) {
            int chb = (kk >> 3) + lhi;
            short8 a[4];
            #pragma unroll
            for (int m = 0; m < 4; ++m) {
                int r = wr * 64 + m * 16 + l15;
                a[m] = *(const short8*)&LA[r][(chb ^ (r & 7)) * 8];
            }
            #pragma unroll
            for (int n = 0; n < NF; ++n) {
                int c = wc * (BN / 4) + n * 16 + l15;
                short8 b = *(const short8*)&LB[c][(chb ^ (c & 7)) * 8];
                #pragma unroll
                for (int m = 0; m < 4; ++m)
                    acc[m][n] = __builtin_amdgcn_mfma_f32_16x16x32_bf16(a[m], b, acc[m][n], 0, 0, 0);
            }
        }
    }

    #pragma unroll
    for (int n = 0; n < NF; ++n) {
        int col = wc * (BN / 4) + n * 16 + l15;
        float bv = bias ? bias[col] : 0.f;
        #pragma unroll
        for (int m = 0; m < 4; ++m) {
            #pragma unroll
            for (int j = 0; j < 4; ++j) {
                int gr = row0 + wr * 64 + m * 16 + (lhi << 2) + j;
                if (gr < N) {
                    float v = acc[m][n][j] + bv;
                    if (act) v = fmaxf(v, 0.f);
                    long off;
                    if (interleaved) {
                        int cc = col & 127;
                        off = (long)gr * 256 + 4 * (cc >> 1) + ((col >> 7) << 1) + (cc & 1);
                    } else {
                        off = (long)gr * o_stride + col;
                    }
                    out[off] = f2bu(v);
                }
            }
        }
    }
}

// ---------------- fused gin2 -> next-layer dual GEMM ----------------
// Stage 1: X = relu(h1 @ Wg2^T + b2) into LDS XT (never hits global).
// Stage 2: yh = [X | s] @ Wd^T, A from XT (k<128) / xc s-half (k>=128).
// 8 waves, BM=128; LDS = XT 32K + SB 32K + SA 16K = 80 KB (2 blocks/CU).

__global__ __launch_bounds__(512) void fused_g2d(
    const ushort* __restrict__ h1,      // [N][128]
    const ushort* __restrict__ xcs,     // [N][256], s at cols 128..255
    const ushort* __restrict__ Wg2,     // [128][128]
    const float*  __restrict__ b2,
    const ushort* __restrict__ Wd,      // [256][256]
    ushort* __restrict__ yh, int N)
{
    __shared__ __align__(16) ushort XT[128][128];
    __shared__ __align__(16) ushort SB[256][64];
    __shared__ __align__(16) ushort SA[128][64];

    const int tid  = threadIdx.x;
    const int l    = tid & 63;
    const int w    = tid >> 6;
    const int wr   = w >> 2;
    const int wc   = w & 3;
    const int row0 = blockIdx.x * 128;
    const int l15  = l & 15;
    const int lhi  = l >> 4;
    const int lrow = l >> 3;
    const int lslot = l & 7;

    // ---- phase 1 ----
    f32x4 ax[4][2];
    #pragma unroll
    for (int m = 0; m < 4; ++m)
        #pragma unroll
        for (int n = 0; n < 2; ++n) ax[m][n] = (f32x4){0.f, 0.f, 0.f, 0.f};

    #pragma unroll
    for (int k0 = 0; k0 < 128; k0 += 64) {
        __syncthreads();
        #pragma unroll
        for (int i = 0; i < 2; ++i) {
            int ci = w * 2 + i;
            int r  = ci * 8 + lrow;
            int gr = row0 + r; if (gr > N - 1) gr = N - 1;
            gload16(h1 + (long)gr * 128 + k0 + ((lslot ^ (r & 7)) * 8), &SA[ci * 8][0]);
        }
        #pragma unroll
        for (int i = 0; i < 2; ++i) {
            int ci = w * 2 + i;
            int c  = ci * 8 + lrow;
            gload16(Wg2 + (long)c * 128 + k0 + ((lslot ^ (c & 7)) * 8), &SB[ci * 8][0]);
        }
        __syncthreads();
        #pragma unroll
        for (int kk = 0; kk < 64; kk += 32) {
            int chb = (kk >> 3) + lhi;
            short8 a[4];
            #pragma unroll
            for (int m = 0; m < 4; ++m) {
                int r = wr * 64 + m * 16 + l15;
                a[m] = *(const short8*)&SA[r][(chb ^ (r & 7)) * 8];
            }
            #pragma unroll
            for (int n = 0; n < 2; ++n) {
                int c = wc * 32 + n * 16 + l15;
                short8 b = *(const short8*)&SB[c][(chb ^ (c & 7)) * 8];
                #pragma unroll
                for (int m = 0; m < 4; ++m)
                    ax[m][n] = __builtin_amdgcn_mfma_f32_16x16x32_bf16(a[m], b, ax[m][n], 0, 0, 0);
            }
        }
    }
    // write X tile to XT (relu + bias), XOR-swizzled chunks
    #pragma unroll
    for (int n = 0; n < 2; ++n) {
        int col = wc * 32 + n * 16 + l15;
        float bv = b2[col];
        #pragma unroll
        for (int m = 0; m < 4; ++m) {
            #pragma unroll
            for (int j = 0; j < 4; ++j) {
                int row = wr * 64 + m * 16 + (lhi << 2) + j;
                float v = fmaxf(ax[m][n][j] + bv, 0.f);
                XT[row][(((col >> 3) ^ (row & 7)) << 3) + (col & 7)] = f2bu(v);
            }
        }
    }

    // ---- phase 2 ----
    f32x4 ay[4][4];
    #pragma unroll
    for (int m = 0; m < 4; ++m)
        #pragma unroll
        for (int n = 0; n < 4; ++n) ay[m][n] = (f32x4){0.f, 0.f, 0.f, 0.f};

    #pragma unroll
    for (int k0 = 0; k0 < 256; k0 += 64) {
        __syncthreads();
        if (k0 >= 128) {
            #pragma unroll
            for (int i = 0; i < 2; ++i) {
                int ci = w * 2 + i;
                int r  = ci * 8 + lrow;
                int gr = row0 + r; if (gr > N - 1) gr = N - 1;
                gload16(xcs + (long)gr * 256 + 128 + (k0 - 128) + ((lslot ^ (r & 7)) * 8),
                        &SA[ci * 8][0]);
            }
        }
        #pragma unroll
        for (int i = 0; i < 4; ++i) {
            int ci = w * 4 + i;
            int c  = ci * 8 + lrow;
            gload16(Wd + (long)c * 256 + k0 + ((lslot ^ (c & 7)) * 8), &SB[ci * 8][0]);
        }
        __syncthreads();
        #pragma unroll
        for (int kk = 0; kk < 64; kk += 32) {
            short8 a[4];
            if (k0 < 128) {
                int chb = ((k0 + kk) >> 3) + lhi;
                #pragma unroll
                for (int m = 0; m < 4; ++m) {
                    int r = wr * 64 + m * 16 + l15;
                    a[m] = *(const short8*)&XT[r][(chb ^ (r & 7)) * 8];
                }
            } else {
                int chb = (kk >> 3) + lhi;
                #pragma unroll
                for (int m = 0; m < 4; ++m) {
                    int r = wr * 64 + m * 16 + l15;
                    a[m] = *(const short8*)&SA[r][(chb ^ (r & 7)) * 8];
                }
            }
            int chbb = (kk >> 3) + lhi;
            #pragma unroll
            for (int n = 0; n < 4; ++n) {
                int c = wc * 64 + n * 16 + l15;
                short8 b = *(const short8*)&SB[c][(chbb ^ (c & 7)) * 8];
                #pragma unroll
                for (int m = 0; m < 4; ++m)
                    ay[m][n] = __builtin_amdgcn_mfma_f32_16x16x32_bf16(a[m], b, ay[m][n], 0, 0, 0);
            }
        }
    }

    // epilogue: interleaved yh write
    #pragma unroll
    for (int n = 0; n < 4; ++n) {
        int col = wc * 64 + n * 16 + l15;
        int cc = col & 127;
        #pragma unroll
        for (int m = 0; m < 4; ++m) {
            #pragma unroll
            for (int j = 0; j < 4; ++j) {
                int gr = row0 + wr * 64 + m * 16 + (lhi << 2) + j;
                if (gr < N) {
                    long off = (long)gr * 256 + 4 * (cc >> 1) + ((col >> 7) << 1) + (cc & 1);
                    yh[off] = f2bu(ay[m][n][j]);
                }
            }
        }
    }
}

// ---------------- fused GIN+GCN gather (scalar edge records, unroll-16 + masked-4 tail) ----------------

__global__ __launch_bounds__(256) void fused_gather(
    const uint2* __restrict__ yh, const int* __restrict__ offs,
    const int2* __restrict__ epack,
    const float* __restrict__ dinv,
    const float* __restrict__ b1, const float* __restrict__ gb,
    uint* __restrict__ h1p, uint* __restrict__ xcp, int N)
{
    int node = blockIdx.x * 4 + (threadIdx.x >> 6);
    if (node >= N) return;
    node = __builtin_amdgcn_readfirstlane(node);
    int l = threadIdx.x & 63;

    uint2 self = yh[(long)node * 64 + l];
    float di = dinv[node];
    float g0 = blo(self.x), g1 = bhi(self.x);
    float s0 = 0.f, s1 = 0.f;

    int j0 = __builtin_amdgcn_readfirstlane(offs[node]);
    int j1 = __builtin_amdgcn_readfirstlane(offs[node + 1]);
    int jmid = j0 + ((j1 - j0) & ~15);

    for (int j = j0; j < jmid; j += 16) {
        int2 e[16]; uint2 v[16];
        #pragma unroll
        for (int k = 0; k < 16; ++k) e[k] = epack[j + k];
        #pragma unroll
        for (int k = 0; k < 16; ++k) v[k] = yh[e[k].x + l];
        #pragma unroll
        for (int k = 0; k < 16; ++k) {
            float ds = __int_as_float(e[k].y);
            g0 += blo(v[k].x);
            g1 += bhi(v[k].x);
            s0 += blo(v[k].y) * ds;
            s1 += bhi(v[k].y) * ds;
        }
    }
    for (int j = jmid; j < j1; j += 4) {
        int2 e[4]; uint2 v[4];
        #pragma unroll
        for (int k = 0; k < 4; ++k) {
            int jj = j + k;
            e[k] = epack[(jj < j1) ? jj : (j1 - 1)];
            if (jj >= j1) e[k].y = 0;
        }
        #pragma unroll
        for (int k = 0; k < 4; ++k) v[k] = yh[e[k].x + l];
        #pragma unroll
        for (int k = 0; k < 4; ++k) {
            float ds = __int_as_float(e[k].y);
            float m = (j + k < j1) ? 1.f : 0.f;
            g0 += blo(v[k].x) * m;
            g1 += bhi(v[k].x) * m;
            s0 += blo(v[k].y) * ds;
            s1 += bhi(v[k].y) * ds;
        }
    }

    float2 bb = ((const float2*)b1)[l];
    g0 = fmaxf(g0 + bb.x, 0.f);
    g1 = fmaxf(g1 + bb.y, 0.f);
    h1p[(long)node * 64 + l] = packbf(g0, g1);

    float dii = di * di;
    float2 gg = ((const float2*)gb)[l];
    float t0 = tanhf(s0 * di + blo(self.y) * dii + gg.x);
    float t1 = tanhf(s1 * di + bhi(self.y) * dii + gg.y);
    xcp[(long)node * 128 + 64 + l] = packbf(t0, t1);
}

// ---------------- pooling: gsum[G][256] = per-graph sum of xc rows; cntg = node counts ----------------

__global__ void pool_kernel(const ushort* __restrict__ xc, const int* __restrict__ batch,
                            float* __restrict__ gsum, int* __restrict__ cntg, int N) {
    int c  = threadIdx.x;    // 256 channels
    int n0 = blockIdx.x * 128;
    if (n0 >= N) return;
    int n1 = min(n0 + 128, N);
    int curg = batch[n0];
    float acc = 0.f;
    int cnt = 0;
    for (int n = n0; n < n1; ++n) {
        int b = batch[n];
        if (b != curg) {
            atomicAdd(&gsum[(long)curg * 256 + c], acc);
            if (c == 0) atomicAdd(&cntg[curg], cnt);
            acc = 0.f; cnt = 0;
            curg = b;
        }
        acc += blo((uint)xc[(long)n * 256 + c]);
        cnt++;
    }
    atomicAdd(&gsum[(long)curg * 256 + c], acc);
    if (c == 0) atomicAdd(&cntg[curg], cnt);
}

// ---------------- head: whp + post + readout + log_softmax ----------------

__global__ void head_kernel(const float* __restrict__ gsum, const int* __restrict__ cntg,
                            const float* __restrict__ whp_w, const float* __restrict__ whp_b,
                            const float* __restrict__ post_w, const float* __restrict__ post_b,
                            const float* __restrict__ ro_w, const float* __restrict__ ro_b,
                            float* __restrict__ out, int C) {
    __shared__ float row[256];
    __shared__ float xr[128];
    __shared__ float g2[128];
    __shared__ float lg[16];
    __shared__ float s_lse;
    int gi = blockIdx.x;
    int c  = threadIdx.x;   // 128
    row[c]       = gsum[(long)gi * 256 + c];
    row[c + 128] = gsum[(long)gi * 256 + 128 + c];
    __syncthreads();
    float cntf = (float)cntg[gi];
    float acc = cntf * whp_b[c];
    for (int k = 0; k < 256; ++k) acc += row[k] * whp_w[(long)k * 128 + c];
    xr[c] = acc;
    __syncthreads();
    float a2 = post_b[c];
    for (int k = 0; k < 128; ++k) a2 += xr[k] * post_w[k * 128 + c];
    g2[c] = fmaxf(a2, 0.f);
    __syncthreads();
    if (c < C) {
        float a = ro_b[c];
        for (int k = 0; k < 128; ++k) a += g2[k] * ro_w[k * C + c];
        lg[c] = a;
    }
    __syncthreads();
    if (c == 0) {
        float m = lg[0];
        for (int i = 1; i < C; ++i) m = fmaxf(m, lg[i]);
        float sum = 0.f;
        for (int i = 0; i < C; ++i) sum += expf(lg[i] - m);
        s_lse = m + logf(sum);
    }
    __syncthreads();
    if (c < C) out[(long)gi * C + c] = lg[c] - s_lse;
}

// ---------------- launch ----------------

extern "C" void kernel_launch(void* const* d_in, const int* in_sizes, int n_in,
                              void* d_out, int out_size, void* d_ws, size_t ws_size,
                              hipStream_t stream) {
    const float* x      = (const float*)d_in[0];
    const float* s_in   = (const float*)d_in[1];
    const int*   ei     = (const int*)d_in[2];
    const int*   batch  = (const int*)d_in[3];
    const float* pre_w  = (const float*)d_in[4];
    const float* pre_b  = (const float*)d_in[5];
    const float* emb_w  = (const float*)d_in[6];
    const float* emb_b  = (const float*)d_in[7];
    const float* gin_w1 = (const float*)d_in[8];
    const float* gin_b1 = (const float*)d_in[9];
    const float* gin_w2 = (const float*)d_in[10];
    const float* gin_b2 = (const float*)d_in[11];
    const float* gcn_w  = (const float*)d_in[12];
    const float* gcn_b  = (const float*)d_in[13];
    const float* whp_w  = (const float*)d_in[14];
    const float* whp_b  = (const float*)d_in[15];
    const float* post_w = (const float*)d_in[16];
    const float* post_b = (const float*)d_in[17];
    const float* ro_w   = (const float*)d_in[18];
    const float* ro_b   = (const float*)d_in[19];

    const int H = 128;
    const int N = in_sizes[0] / 128;
    const int E = in_sizes[2] / 2;
    const int C = in_sizes[19];
    const int G = out_size / C;
    const int L = in_sizes[9] / H;

    const int* srcv = ei;
    const int* dstv = ei + E;

    char* p = (char*)d_ws;
    auto alloc = [&](size_t bytes) -> void* {
        void* r = (void*)p;
        p += (bytes + 255) & ~(size_t)255;
        return r;
    };
    ushort* xc   = (ushort*)alloc((size_t)N * 256 * 2);
    ushort* yh   = (ushort*)alloc((size_t)N * 256 * 2);
    ushort* h1   = (ushort*)alloc((size_t)N * 128 * 2);
    ushort* xs   = (ushort*)alloc((size_t)N * 192 * 2);
    ushort* Wt_preemb = (ushort*)alloc(256 * 192 * 2);
    ushort* Wt_dual   = (ushort*)alloc((size_t)L * 256 * 256 * 2);
    ushort* Wt_gin2   = (ushort*)alloc((size_t)L * 128 * 128 * 2);
    float*  bias_comb = (float*)alloc(256 * 4);
    float*  dinv = (float*)alloc((size_t)N * 4);
    float*  gsum = (float*)alloc((size_t)G * 256 * 4);
    int*    cntg = (int*)alloc((size_t)G * 4);
    int* cnt   = (int*)alloc((size_t)N * 4);
    int* offs  = (int*)alloc((size_t)(N + 1) * 4);
    int* rank  = (int*)alloc((size_t)E * 4);
    int* bsum  = (int*)alloc((size_t)HGRID(N, 1024) * 4);
    int2* epack = (int2*)alloc((size_t)E * 8);

    const int nb = HGRID(N, 1024);

    SetupArgs sa;
    sa.x = x; sa.s = s_in;
    sa.pre_w = pre_w; sa.pre_b = pre_b; sa.emb_w = emb_w; sa.emb_b = emb_b;
    sa.gin_w1 = gin_w1; sa.gcn_w = gcn_w; sa.gin_w2 = gin_w2;
    sa.xs = xs; sa.Wt_preemb = Wt_preemb; sa.Wt_dual = Wt_dual; sa.Wt_gin2 = Wt_gin2;
    sa.bias_comb = bias_comb; sa.cnt = cnt; sa.gsum = gsum; sa.cntg = cntg;
    sa.L = L; sa.N = N; sa.G = G;
    long setup_tot = (long)N * 24 + 49152 + (long)L * 65536 + (long)L * 16384 + 256
                   + N + (long)G * 256 + G;
    setup_kernel<<<HGRID(setup_tot, 256), 256, 0, stream>>>(sa);

    count_kernel<<<HGRID(E, 256), 256, 0, stream>>>(dstv, cnt, rank, E);
    scan_part<<<nb, 256, 0, stream>>>(cnt, bsum, N);
    scan_fill<<<nb, 256, 0, stream>>>(cnt, bsum, offs, dinv, N, E);
    fill_kernel<<<HGRID(E, 256), 256, 0, stream>>>(srcv, dstv, offs, rank, dinv, epack, E);

    const int lb = HGRID(N, 128);
    lin_mfma<192, 256><<<lb, 512, 0, stream>>>(xs, 192, Wt_preemb, bias_comb,
                                               xc, 256, N, 0, 0);
    // first dual GEMM
    lin_mfma<256, 256><<<lb, 512, 0, stream>>>(xc, 256, Wt_dual, nullptr, yh, 256, N, 0, 1);

    for (int i = 0; i < L; ++i) {
        fused_gather<<<HGRID(N, 4), 256, 0, stream>>>(
            (const uint2*)yh, offs, epack, dinv,
            gin_b1 + (size_t)i * H, gcn_b + (size_t)i * H,
            (uint*)h1, (uint*)xc, N);
        if (i < L - 1) {
            // fused: yh_{i+1} = relu(h1@gin2_i+b2_i) @ top_{i+1} + s_{i+1} @ bot_{i+1}
            fused_g2d<<<lb, 512, 0, stream>>>(
                h1, xc, Wt_gin2 + (size_t)i * 16384, gin_b2 + (size_t)i * H,
                Wt_dual + (size_t)(i + 1) * 65536, yh, N);
        } else {
            // last layer: x written to xc for pooling
            lin_mfma<128, 128><<<lb, 512, 0, stream>>>(h1, 128, Wt_gin2 + (size_t)i * 16384,
                                                       gin_b2 + (size_t)i * H, xc, 256, N, 1, 0);
        }
    }

    pool_kernel<<<HGRID(N, 128), 256, 0, stream>>>(xc, batch, gsum, cntg, N);
    head_kernel<<<G, 128, 0, stream>>>(gsum, cntg, whp_w, whp_b,
                                       post_w, post_b, ro_w, ro_b, (float*)d_out, C);
}